// Round 8
// baseline (355.420 us; speedup 1.0000x reference)
//
#include <hip/hip_runtime.h>
#include <math.h>

#define D_MODEL 1024
#define NHEAD   16
#define HDIM    64
#define SEQ     2048
#define BATCH   2
#define NROWS   (BATCH*SEQ)   // 4096
#define KSPLIT  2
#define KTILES  (SEQ/64/KSPLIT)   // 16 tiles per split

typedef unsigned short u16;
typedef __attribute__((ext_vector_type(4))) unsigned short u16x4;
typedef __attribute__((ext_vector_type(8))) short short8;
typedef __attribute__((ext_vector_type(4))) float f32x4;
typedef __attribute__((ext_vector_type(2))) unsigned int u32x2;

// XOR-swizzle: 16B chunk c of row r lives at chunk c ^ (r & 7). Applied to all
// 64-u16 (128B) LDS tile rows so every 8-lane phase of a b128 op hits 8 distinct
// bank-quads (T2).
#define SWZ(row, c) (((c) ^ ((row) & 7)) * 8)

// ---- bf16 helpers (RNE) ----
__device__ __forceinline__ u16 f2bf(float x) {
    unsigned int u = __float_as_uint(x);
    u += 0x7fffu + ((u >> 16) & 1u);
    return (u16)(u >> 16);
}
__device__ __forceinline__ float bf2f(u16 h) {
    return __uint_as_float(((unsigned int)h) << 16);
}
// ---- fp16 helpers (HW RNE cvt) ----
__device__ __forceinline__ u16 f2h(float x) {
    _Float16 h = (_Float16)x; u16 r; __builtin_memcpy(&r, &h, 2); return r;
}
__device__ __forceinline__ float h2f(u16 u) {
    _Float16 h; __builtin_memcpy(&h, &u, 2); return (float)h;
}
// packed f32x2 -> bf16x2 (HW RNE), no builtin on gfx950 -> inline asm
__device__ __forceinline__ unsigned int cvt_pk_bf16(float a, float b) {
    unsigned int r;
    asm("v_cvt_pk_bf16_f32 %0, %1, %2" : "=v"(r) : "v"(a), "v"(b));
    return r;
}
// 8-bf16 LDS access via 2x b64 (gemm tiles are 8B-aligned rows)
__device__ __forceinline__ short8 ld8(const u16* p) {
    u16x4 a = *(const u16x4*)p;
    u16x4 b = *(const u16x4*)(p + 4);
    short8 r;
    r[0]=(short)a[0]; r[1]=(short)a[1]; r[2]=(short)a[2]; r[3]=(short)a[3];
    r[4]=(short)b[0]; r[5]=(short)b[1]; r[6]=(short)b[2]; r[7]=(short)b[3];
    return r;
}
__device__ __forceinline__ void st8(u16* p, short8 v) {
    u16x4 a, b;
    a[0]=(u16)v[0]; a[1]=(u16)v[1]; a[2]=(u16)v[2]; a[3]=(u16)v[3];
    b[0]=(u16)v[4]; b[1]=(u16)v[5]; b[2]=(u16)v[6]; b[3]=(u16)v[7];
    *(u16x4*)p = a; *(u16x4*)(p + 4) = b;
}

// ---------------------------------------------------------------- gdiag
__global__ void gdiag_kernel(const float* __restrict__ A,
                             const float* __restrict__ log_lambda,
                             float* __restrict__ gdiag) {
    int id = blockIdx.x * 256 + threadIdx.x;
    if (id >= NHEAD * HDIM) return;
    int h = id >> 6, d = id & 63;
    float s = 0.f;
#pragma unroll
    for (int i = 0; i < 16; ++i) {
        float a = A[(h * 16 + i) * HDIM + d];
        s += a * a;
    }
    gdiag[id] = (s + __expf(log_lambda[h])) * 1.4426950408889634f;
}

// ---------------------------------------------------------------- prep: fp32 -> bf16 hi/lo
__global__ void prep_split(const float* __restrict__ x,
                           const float* __restrict__ Wq, const float* __restrict__ Wk,
                           const float* __restrict__ Wv, const float* __restrict__ Wo,
                           u16* __restrict__ xh, u16* __restrict__ xl,
                           u16* __restrict__ wqh, u16* __restrict__ wql,
                           u16* __restrict__ wkh, u16* __restrict__ wkl,
                           u16* __restrict__ wvh, u16* __restrict__ woh) {
    int seg = blockIdx.y;
    int i = blockIdx.x * 256 + threadIdx.x;   // float4 index
    const float* src; u16* dh; u16* dl; int n4;
    if      (seg == 0) { src = x;  dh = xh;  dl = xl;      n4 = NROWS * D_MODEL / 4; }
    else if (seg == 1) { src = Wq; dh = wqh; dl = wql;     n4 = D_MODEL * D_MODEL / 4; }
    else if (seg == 2) { src = Wk; dh = wkh; dl = wkl;     n4 = D_MODEL * D_MODEL / 4; }
    else if (seg == 3) { src = Wv; dh = wvh; dl = nullptr; n4 = D_MODEL * D_MODEL / 4; }
    else               { src = Wo; dh = woh; dl = nullptr; n4 = D_MODEL * D_MODEL / 4; }
    if (i >= n4) return;
    float4 v = *(const float4*)&src[(size_t)i * 4];
    float vv[4] = {v.x, v.y, v.z, v.w};
    u16x4 hv, lv;
#pragma unroll
    for (int j = 0; j < 4; ++j) {
        u16 hb = f2bf(vv[j]);
        hv[j] = hb;
        lv[j] = f2bf(vv[j] - bf2f(hb));
    }
    *(u16x4*)&dh[(size_t)i * 4] = hv;
    if (dl) *(u16x4*)&dl[(size_t)i * 4] = lv;
}

// ---------------------------------------------------------------- MFMA NT GEMM
// out[r][c] = sum_k A[r][k]*W[c][k] + bias[c]; A,W in bf16 hi(/lo), fp32 acc.
template<int NP3>
__global__ __launch_bounds__(256)
void gemm_mfma(const u16* __restrict__ Ah, const u16* __restrict__ Al,
               const u16* __restrict__ BhA, const u16* __restrict__ BlA, const float* __restrict__ biasA,
               float* outfA, u16* auxhA, u16* auxlA, float* ksumA,
               const u16* __restrict__ BhB, const u16* __restrict__ BlB, const float* __restrict__ biasB,
               float* outfB, u16* auxhB, u16* auxlB, float* ksumB,
               int out_layout) {
    const int z = blockIdx.z;
    const u16* Bh = (z == 0) ? BhA : BhB;
    const u16* Bl = (z == 0) ? BlA : BlB;
    const float* bias = (z == 0) ? biasA : biasB;
    float* outf = (z == 0) ? outfA : outfB;
    u16* auxh   = (z == 0) ? auxhA : auxhB;
    u16* auxl   = (z == 0) ? auxlA : auxlB;
    float* ksump= (z == 0) ? ksumA : ksumB;

    __shared__ u16 As_h[128][36], Bs_h[128][36];
    __shared__ u16 As_l[128][36], Bs_l[128][36];

    const int tid = threadIdx.x;
    const int w = tid >> 6, lane = tid & 63, quad = lane >> 4, n16 = lane & 15;
    const int rBase = blockIdx.y * 128;
    const int cBase = blockIdx.x * 128;

    f32x4 acc[2][8] = {};

    for (int kt = 0; kt < D_MODEL; kt += 32) {
#pragma unroll
        for (int s = 0; s < 2; ++s) {
            int id = s * 256 + tid;          // 512 chunks of 8 bf16
            int row = id >> 2;
            int c8 = (id & 3) * 8;
            st8(&As_h[row][c8], *(const short8*)&Ah[(size_t)(rBase + row) * D_MODEL + kt + c8]);
            st8(&Bs_h[row][c8], *(const short8*)&Bh[(size_t)(cBase + row) * D_MODEL + kt + c8]);
            if (NP3) {
                st8(&As_l[row][c8], *(const short8*)&Al[(size_t)(rBase + row) * D_MODEL + kt + c8]);
                st8(&Bs_l[row][c8], *(const short8*)&Bl[(size_t)(cBase + row) * D_MODEL + kt + c8]);
            }
        }
        __syncthreads();

        short8 a_h[2], a_l[2];
#pragma unroll
        for (int mt = 0; mt < 2; ++mt) {
            a_h[mt] = ld8(&As_h[w * 32 + mt * 16 + n16][quad * 8]);
            if (NP3) a_l[mt] = ld8(&As_l[w * 32 + mt * 16 + n16][quad * 8]);
        }
#pragma unroll
        for (int nt = 0; nt < 8; ++nt) {
            short8 b_h = ld8(&Bs_h[nt * 16 + n16][quad * 8]);
            short8 b_l;
            if (NP3) b_l = ld8(&Bs_l[nt * 16 + n16][quad * 8]);
#pragma unroll
            for (int mt = 0; mt < 2; ++mt) {
                acc[mt][nt] = __builtin_amdgcn_mfma_f32_16x16x32_bf16(a_h[mt], b_h, acc[mt][nt], 0, 0, 0);
                if (NP3) {
                    acc[mt][nt] = __builtin_amdgcn_mfma_f32_16x16x32_bf16(a_h[mt], b_l, acc[mt][nt], 0, 0, 0);
                    acc[mt][nt] = __builtin_amdgcn_mfma_f32_16x16x32_bf16(a_l[mt], b_h, acc[mt][nt], 0, 0, 0);
                }
            }
        }
        __syncthreads();
    }

    // epilogue: C row = quad*4+reg (within 16x16 tile), col = n16
    float csum[8];
#pragma unroll
    for (int nt = 0; nt < 8; ++nt) csum[nt] = 0.f;
#pragma unroll
    for (int mt = 0; mt < 2; ++mt) {
#pragma unroll
        for (int nt = 0; nt < 8; ++nt) {
            int c = cBase + nt * 16 + n16;
            float bc = bias[c];
            int rb = rBase + w * 32 + mt * 16 + quad * 4;
#pragma unroll
            for (int reg = 0; reg < 4; ++reg) {
                float val = acc[mt][nt][reg] + bc;
                int rr = rb + reg;
                size_t idx = out_layout
                    ? ((size_t)(((rr >> 11) * NHEAD + (c >> 6)) * SEQ + (rr & (SEQ - 1)))) * HDIM + (c & 63)
                    : (size_t)rr * D_MODEL + c;
                if (outf) outf[idx] = val;
                if (auxh) {
                    u16 hb = f2bf(val);
                    auxh[idx] = hb;
                    if (auxl) auxl[idx] = f2bf(val - bf2f(hb));
                }
                csum[nt] += val;
            }
        }
    }
    if (ksump) {
#pragma unroll
        for (int nt = 0; nt < 8; ++nt) {
            float cs = csum[nt];
            cs += __shfl_xor(cs, 16);
            cs += __shfl_xor(cs, 32);
            if (quad == 0) {
                int c = cBase + nt * 16 + n16;
                int bb = rBase >> 11;
                atomicAdd(&ksump[(bb * NHEAD + (c >> 6)) * HDIM + (c & 63)], cs);
            }
        }
    }
}

// ---------------------------------------------------------------- v transpose: (b,h,t,hd) bf16 -> (b,h,hd,t) bf16
__global__ __launch_bounds__(256)
void vtrans_kernel(const u16* __restrict__ vh, u16* __restrict__ vT) {
    __shared__ u16 tile[64][72];
    const int tid = threadIdx.x;
    const int t0 = blockIdx.x * 64;
    const int bh = blockIdx.y;
    const u16* vp = vh + (size_t)bh * SEQ * HDIM;
#pragma unroll
    for (int s = 0; s < 2; ++s) {
        int id = s * 256 + tid;
        int row = id >> 3, c8 = (id & 7) * 8;
        st8(&tile[row][c8], *(const short8*)&vp[(size_t)(t0 + row) * HDIM + c8]);
    }
    __syncthreads();
#pragma unroll
    for (int s = 0; s < 2; ++s) {
        int id = s * 256 + tid;
        int d = id >> 3, t8 = (id & 7) * 8;
        short8 r;
#pragma unroll
        for (int i = 0; i < 8; ++i) r[i] = (short)tile[t8 + i][d];
        *(short8*)&vT[((size_t)bh * HDIM + d) * SEQ + t0 + t8] = r;
    }
}

// ---------------------------------------------------------------- flash attention, split-K (flash-decoding)
// RESUBMISSION of r7 (container infra failure; source audited: all global/LDS indices
// in-bounds, no new API calls, structure = passing r5/r6).
// Grid x = (SEQ/128)*KSPLIT: qblk = x>>1, split = x&1. Each block: 128 queries x 1024 keys.
// REGISTER BUDGET: per-SIMD pool 512 regs, HW quanta {64,128,256}; r6 = 100 VGPR + 64
// AGPR = 164 -> 256 bucket -> 2 waves/SIMD (measured 20%). To reach 4 waves/SIMD the
// kernel must fit 128 total. Cuts vs r6:
//  (a) no register-carried staging (inline load->store at tile top; TLP hides latency),
//  (b) HALF-TILE softmax: 32-key halves -> live logit block 16 regs not 32.
// Est. split: ~48 AGPR (oaccv+lgH) + ~70 VGPR -> 128 bucket.
// __launch_bounds__(256,4) pins the cap.
// logits(log2) = Sg . k; swapped operands; T13 defer-max; lane-local l; XOR-swizzle (T2).
__global__ __launch_bounds__(256, 4)
void flash_mfma(const float* __restrict__ q, const u16* __restrict__ kh,
                const u16* __restrict__ kl, const u16* __restrict__ vT,
                const float* __restrict__ ksum, const float* __restrict__ gdiag,
                u16* __restrict__ opart0, u16* __restrict__ opart1,
                float* __restrict__ mlbuf) {
    __shared__ __align__(16) u16 khs[64][64], kls[64][64], vTs[64][64];
    __shared__ __align__(16) u16 ps[4][32][64];

    const int tid = threadIdx.x;
    const int w = tid >> 6, lane = tid & 63, quad = lane >> 4, n16 = lane & 15;
    const int qblk = blockIdx.x >> 1, split = blockIdx.x & 1;
    const int t0 = qblk * 128;
    const int jbase = split * (SEQ / KSPLIT);
    const int h = blockIdx.y, b = blockIdx.z;
    const size_t bh = (size_t)b * NHEAD + h;
    const float* qp = q + bh * SEQ * HDIM;
    const u16* khp = kh + bh * SEQ * HDIM;
    const u16* klp = kl + bh * SEQ * HDIM;
    const u16* vtp = vT + bh * HDIM * SEQ;
    u16* opart = split ? opart1 : opart0;

    // Sg fragments: sg*[mt][kc][j], d = kc*32 + quad*8 + j, query = t0+w*32+mt*16+n16
    short8 sgh[2][2], sgl[2][2];
#pragma unroll
    for (int mt = 0; mt < 2; ++mt) {
        int qrow = t0 + w * 32 + mt * 16 + n16;
#pragma unroll
        for (int kc = 0; kc < 2; ++kc) {
            int d0 = kc * 32 + quad * 8;
            float4 q0 = *(const float4*)&qp[(size_t)qrow * HDIM + d0];
            float4 q1 = *(const float4*)&qp[(size_t)qrow * HDIM + d0 + 4];
            float4 k0 = *(const float4*)&ksum[bh * HDIM + d0];
            float4 k1 = *(const float4*)&ksum[bh * HDIM + d0 + 4];
            float4 g0 = *(const float4*)&gdiag[(size_t)h * HDIM + d0];
            float4 g1 = *(const float4*)&gdiag[(size_t)h * HDIM + d0 + 4];
            float sg[8];
            sg[0] = (2048.f * q0.x - k0.x) * g0.x; sg[1] = (2048.f * q0.y - k0.y) * g0.y;
            sg[2] = (2048.f * q0.z - k0.z) * g0.z; sg[3] = (2048.f * q0.w - k0.w) * g0.w;
            sg[4] = (2048.f * q1.x - k1.x) * g1.x; sg[5] = (2048.f * q1.y - k1.y) * g1.y;
            sg[6] = (2048.f * q1.z - k1.z) * g1.z; sg[7] = (2048.f * q1.w - k1.w) * g1.w;
#pragma unroll
            for (int j = 0; j < 8; ++j) {
                u16 hb = f2bf(sg[j]);
                sgh[mt][kc][j] = (short)hb;
                sgl[mt][kc][j] = (short)f2bf(sg[j] - bf2f(hb));
            }
        }
    }

    f32x4 oaccv[2][4] = {};
    float m_n[2] = {-INFINITY, -INFINITY};
    float l_n[2] = {0.f, 0.f};     // LANE-LOCAL partial sums (16 keys/lane); reduced in epilogue

    // staging: thread owns rows {srow, srow+32}, chunk sc; LDS col swizzled.
    const int srow = tid >> 3;            // 0..31
    const int sc   = tid & 7;             // chunk
    const int scg  = sc * 8;              // global u16 col
    const int scl  = SWZ(srow, sc);       // LDS u16 col (same for srow+32)

    for (int it = 0; it < KTILES; ++it) {
        if (it) __syncthreads();          // prev tile's LDS reads done
        const int j0 = jbase + it * 64;
        // stage tile (inline load->store; no register carry across compute)
        *(short8*)&khs[srow][scl]      = *(const short8*)&khp[(size_t)(j0 + srow) * HDIM + scg];
        *(short8*)&khs[srow + 32][scl] = *(const short8*)&khp[(size_t)(j0 + srow + 32) * HDIM + scg];
        *(short8*)&kls[srow][scl]      = *(const short8*)&klp[(size_t)(j0 + srow) * HDIM + scg];
        *(short8*)&kls[srow + 32][scl] = *(const short8*)&klp[(size_t)(j0 + srow + 32) * HDIM + scg];
        *(short8*)&vTs[srow][scl]      = *(const short8*)&vtp[(size_t)srow * SEQ + j0 + scg];
        *(short8*)&vTs[srow + 32][scl] = *(const short8*)&vtp[(size_t)(srow + 32) * SEQ + j0 + scg];
        __syncthreads();

        // two 32-key halves per tile (halves live-logit register block)
#pragma unroll
        for (int half = 0; half < 2; ++half) {
            // QK^T for this half: K fragments read ONCE, used by both mt. 3-pass split bf16.
            f32x4 lgH[2][2] = {};
#pragma unroll
            for (int kc = 0; kc < 2; ++kc) {
#pragma unroll
                for (int nth = 0; nth < 2; ++nth) {
                    const int nt = half * 2 + nth;
                    const int row = nt * 16 + n16;
                    const int cc = SWZ(row, kc * 4 + quad);
                    short8 b_h = *(const short8*)&khs[row][cc];
                    short8 b_l = *(const short8*)&kls[row][cc];
#pragma unroll
                    for (int mt = 0; mt < 2; ++mt) {
                        lgH[mt][nth] = __builtin_amdgcn_mfma_f32_16x16x32_bf16(b_h, sgh[mt][kc], lgH[mt][nth], 0, 0, 0);
                        lgH[mt][nth] = __builtin_amdgcn_mfma_f32_16x16x32_bf16(b_l, sgh[mt][kc], lgH[mt][nth], 0, 0, 0);
                        lgH[mt][nth] = __builtin_amdgcn_mfma_f32_16x16x32_bf16(b_h, sgl[mt][kc], lgH[mt][nth], 0, 0, 0);
                    }
                }
            }

            // half max per query fragment
            float mx[2];
#pragma unroll
            for (int mt = 0; mt < 2; ++mt) {
                float m0 = fmaxf(fmaxf(lgH[mt][0][0], lgH[mt][0][1]), lgH[mt][0][2]);
                m0 = fmaxf(fmaxf(m0, lgH[mt][0][3]), lgH[mt][1][0]);
                m0 = fmaxf(fmaxf(m0, lgH[mt][1][1]), lgH[mt][1][2]);
                m0 = fmaxf(m0, lgH[mt][1][3]);
                m0 = fmaxf(m0, __shfl_xor(m0, 16));
                mx[mt] = fmaxf(m0, __shfl_xor(m0, 32));
            }

            // T13 defer-max: skip rescale while max growth <= 8 (P bounded by 2^8)
            const float need = fmaxf(mx[0] - m_n[0], mx[1] - m_n[1]);
            if (!__all(need <= 8.f)) {
#pragma unroll
                for (int mt = 0; mt < 2; ++mt) {
                    const float mn = fmaxf(m_n[mt], mx[mt]);
                    const float alpha = exp2f(m_n[mt] - mn);
                    m_n[mt] = mn;
                    l_n[mt] *= alpha;
                    const float a0 = __shfl(alpha, quad * 4 + 0);
                    const float a1 = __shfl(alpha, quad * 4 + 1);
                    const float a2 = __shfl(alpha, quad * 4 + 2);
                    const float a3 = __shfl(alpha, quad * 4 + 3);
#pragma unroll
                    for (int nt = 0; nt < 4; ++nt) {
                        oaccv[mt][nt][0] *= a0; oaccv[mt][nt][1] *= a1;
                        oaccv[mt][nt][2] *= a2; oaccv[mt][nt][3] *= a3;
                    }
                }
            }

            // P = exp2(lg - m), packed bf16 to per-wave LDS; lane-local psum
#pragma unroll
            for (int mt = 0; mt < 2; ++mt) {
                const int prow = mt * 16 + n16;
                const float mn = m_n[mt];
                float psum = 0.f;
#pragma unroll
                for (int nth = 0; nth < 2; ++nth) {
                    const int nt = half * 2 + nth;
#pragma unroll
                    for (int r = 0; r < 4; ++r) lgH[mt][nth][r] = exp2f(lgH[mt][nth][r] - mn);
                    u32x2 pk;
                    pk[0] = cvt_pk_bf16(lgH[mt][nth][0], lgH[mt][nth][1]);
                    pk[1] = cvt_pk_bf16(lgH[mt][nth][2], lgH[mt][nth][3]);
                    *(u32x2*)&ps[w][prow][SWZ(prow, nt * 2 + (quad >> 1)) + (quad & 1) * 4] = pk;
                    psum += (lgH[mt][nth][0] + lgH[mt][nth][1]) + (lgH[mt][nth][2] + lgH[mt][nth][3]);
                }
                l_n[mt] += psum;
            }

            // PV for this half: V fragments read ONCE, used by both mt.
            short8 pa[2];
#pragma unroll
            for (int mt = 0; mt < 2; ++mt) {
                const int prow = mt * 16 + n16;
                pa[mt] = *(const short8*)&ps[w][prow][SWZ(prow, quad + 4 * half)];
            }
#pragma unroll
            for (int nt = 0; nt < 4; ++nt) {
                const int row = nt * 16 + n16;
                short8 v = *(const short8*)&vTs[row][SWZ(row, quad + 4 * half)];
#pragma unroll
                for (int mt = 0; mt < 2; ++mt) {
                    oaccv[mt][nt] = __builtin_amdgcn_mfma_f32_16x16x32_bf16(pa[mt], v, oaccv[mt][nt], 0, 0, 0);
                }
            }
        }
    }

    // epilogue: reduce lane-local l; write (m,l) float2 + NORMALIZED partial O (fp16)
#pragma unroll
    for (int mt = 0; mt < 2; ++mt) {
        float l = l_n[mt];
        l += __shfl_xor(l, 16);
        l += __shfl_xor(l, 32);
        l_n[mt] = l;
    }
    float2* ml2 = (float2*)mlbuf;
#pragma unroll
    for (int mt = 0; mt < 2; ++mt) {
        if (quad == 0) {
            int tq = t0 + w * 32 + mt * 16 + n16;
            float2 v; v.x = m_n[mt]; v.y = l_n[mt];
            ml2[(((size_t)split * BATCH + b) * NHEAD + h) * SEQ + tq] = v;
        }
#pragma unroll
        for (int r = 0; r < 4; ++r) {
            float lr = __shfl(l_n[mt], quad * 4 + r);
            float inv = 1.f / lr;
            int t = t0 + w * 32 + mt * 16 + quad * 4 + r;
            size_t rowb = (size_t)(b * SEQ + t) * D_MODEL + h * HDIM;
#pragma unroll
            for (int nt = 0; nt < 4; ++nt) {
                opart[rowb + nt * 16 + n16] = f2h(oaccv[mt][nt][r] * inv);
            }
        }
    }
}

// ---------------------------------------------------------------- split-K combine: merge 2 fp16 partials -> o_hi bf16
// o = (o0*c0 + o1*c1)/(c0+c1), c_s = l_s * 2^(m_s - M), M = max(m0, m1)
__global__ __launch_bounds__(256)
void combine_kernel(const u16* __restrict__ opart0, const u16* __restrict__ opart1,
                    const float* __restrict__ mlbuf, u16* __restrict__ o) {
    int idx = blockIdx.x * 256 + threadIdx.x;   // 8-elem chunk id, NROWS*D_MODEL/8 total
    int row = idx >> 7;                          // 128 chunks per row
    int c8  = idx & 127;
    int h = c8 >> 3;                             // 8 chunks per head
    int b = row >> 11, t = row & (SEQ - 1);
    const float2* ml2 = (const float2*)mlbuf;
    float2 s0 = ml2[((size_t)b * NHEAD + h) * SEQ + t];
    float2 s1 = ml2[(((size_t)BATCH + b) * NHEAD + h) * SEQ + t];
    float M = fmaxf(s0.x, s1.x);
    float c0 = s0.y * exp2f(s0.x - M);
    float c1 = s1.y * exp2f(s1.x - M);
    float inv = 1.f / (c0 + c1);
    c0 *= inv; c1 *= inv;
    size_t off = (size_t)row * D_MODEL + c8 * 8;
    u16x4 a0 = *(const u16x4*)&opart0[off];
    u16x4 a1 = *(const u16x4*)&opart0[off + 4];
    u16x4 b0 = *(const u16x4*)&opart1[off];
    u16x4 b1 = *(const u16x4*)&opart1[off + 4];
    u16x4 r0, r1;
#pragma unroll
    for (int j = 0; j < 4; ++j) {
        r0[j] = f2bf(h2f(a0[j]) * c0 + h2f(b0[j]) * c1);
        r1[j] = f2bf(h2f(a1[j]) * c0 + h2f(b1[j]) * c1);
    }
    *(u16x4*)&o[off] = r0;
    *(u16x4*)&o[off + 4] = r1;
}

// ---------------------------------------------------------------- launcher
extern "C" void kernel_launch(void* const* d_in, const int* in_sizes, int n_in,
                              void* d_out, int out_size, void* d_ws, size_t ws_size,
                              hipStream_t stream) {
    const float* x  = (const float*)d_in[0];
    const float* Wq = (const float*)d_in[1];
    const float* bq = (const float*)d_in[2];
    const float* Wk = (const float*)d_in[3];
    const float* bk = (const float*)d_in[4];
    const float* Wv = (const float*)d_in[5];
    const float* bv = (const float*)d_in[6];
    const float* Wo = (const float*)d_in[7];
    const float* bo = (const float*)d_in[8];
    const float* A  = (const float*)d_in[9];
    const float* ll = (const float*)d_in[10];
    float* out = (float*)d_out;

    const size_t NQKV = (size_t)NROWS * D_MODEL;   // 4,194,304
    const size_t NW = (size_t)D_MODEL * D_MODEL;   // 1,048,576
    char* base = (char*)d_ws;
    float* q_ws = (float*)base;            base += NQKV * 4;
    u16* xh  = (u16*)base;                 base += NQKV * 2;   // reused as o_hi after QKV
    u16* xl  = (u16*)base;                 base += NQKV * 2;   // reused as vT after QKV
    u16* khw = (u16*)base;                 base += NQKV * 2;
    u16* klw = (u16*)base;                 base += NQKV * 2;
    u16* vhw = (u16*)base;                 base += NQKV * 2;   // reused as opart0 (fp16) after vtrans
    u16* wqh = (u16*)base;                 base += NW * 2;     // wqh..wkl reused as opart1 (fp16, 8MB)
    u16* wql = (u16*)base;                 base += NW * 2;
    u16* wkh = (u16*)base;                 base += NW * 2;
    u16* wkl = (u16*)base;                 base += NW * 2;
    u16* wvh = (u16*)base;                 base += NW * 2;     // reused as mlbuf (1MB) after V GEMM
    u16* woh = (u16*)base;                 base += NW * 2;     // ALIVE until out-proj
    float* gd_ws   = (float*)base;         base += NHEAD * HDIM * 4;
    float* ksum_ws = (float*)base;         base += BATCH * NHEAD * HDIM * 4;

    hipMemsetAsync(ksum_ws, 0, BATCH * NHEAD * HDIM * sizeof(float), stream);

    prep_split<<<dim3(4096, 5), 256, 0, stream>>>(x, Wq, Wk, Wv, Wo,
                                                  xh, xl, wqh, wql, wkh, wkl, wvh, woh);
    gdiag_kernel<<<4, 256, 0, stream>>>(A, ll, gd_ws);

    // Q (z=0) + K (z=1): 3-pass split-bf16; K writes k_hi/k_lo + ksum atomics
    gemm_mfma<1><<<dim3(8, 32, 2), 256, 0, stream>>>(
        xh, xl,
        wqh, wql, bq, q_ws, nullptr, nullptr, nullptr,
        wkh, wkl, bk, nullptr, khw, klw, ksum_ws,
        1);
    // V: 1-pass bf16, writes v_hi bf16 only
    gemm_mfma<0><<<dim3(8, 32, 1), 256, 0, stream>>>(
        xh, nullptr,
        wvh, nullptr, bv, nullptr, vhw, nullptr, nullptr,
        wvh, nullptr, bv, nullptr, vhw, nullptr, nullptr,
        1);

    u16* vTw = xl;   // alias: x_lo dead after QKV GEMMs
    u16* ohw = xh;   // alias: x_hi dead after QKV GEMMs
    vtrans_kernel<<<dim3(SEQ / 64, BATCH * NHEAD), 256, 0, stream>>>(vhw, vTw);

    // aliases onto DEAD regions (all within the proven workspace footprint):
    u16* opart0 = vhw;            // 8MB: V bf16 dead after vtrans
    u16* opart1 = wqh;            // 8MB: wqh+wql+wkh+wkl weight copies dead after QKV GEMMs
    float* ml_ws = (float*)wvh;   // 1MB needed, 2MB region; Wv copy dead after V GEMM

    flash_mfma<<<dim3((SEQ / 128) * KSPLIT, NHEAD, BATCH), 256, 0, stream>>>(
        q_ws, khw, klw, vTw, ksum_ws, gd_ws, opart0, opart1, ml_ws);

    combine_kernel<<<NROWS * D_MODEL / 8 / 256, 256, 0, stream>>>(opart0, opart1, ml_ws, ohw);

    // out-proj: 1-pass bf16, row-major fp32 output
    gemm_mfma<0><<<dim3(8, 32, 1), 256, 0, stream>>>(
        ohw, nullptr,
        woh, nullptr, bo, out, nullptr, nullptr, nullptr,
        woh, nullptr, bo, out, nullptr, nullptr, nullptr,
        0);
}

// Round 9
// 307.523 us; speedup vs baseline: 1.1558x; 1.1558x over previous
//
#include <hip/hip_runtime.h>
#include <math.h>

#define D_MODEL 1024
#define NHEAD   16
#define HDIM    64
#define SEQ     2048
#define BATCH   2
#define NROWS   (BATCH*SEQ)   // 4096

typedef unsigned short u16;
typedef __attribute__((ext_vector_type(4))) unsigned short u16x4;
typedef __attribute__((ext_vector_type(8))) short short8;
typedef __attribute__((ext_vector_type(4))) float f32x4;
typedef __attribute__((ext_vector_type(2))) unsigned int u32x2;

// Flash LDS swizzle: 16B chunk c of row r lives at chunk c ^ (r & 7) (8 chunks/row).
#define SWZ(row, c) (((c) ^ ((row) & 7)) * 8)
// GEMM LDS swizzle for [*][32] bf16 tiles (4 chunks/row): gives 2-way (free) bank
// aliasing for b128 fragment reads across each 16-lane phase (rows 16a+r, r=0..15:
// f(r) hits each of 4 values exactly twice per parity class).
#define GF(row) ((((row) + ((row) >> 2))) & 3)

// ---- bf16 helpers (RNE) ----
__device__ __forceinline__ u16 f2bf(float x) {
    unsigned int u = __float_as_uint(x);
    u += 0x7fffu + ((u >> 16) & 1u);
    return (u16)(u >> 16);
}
__device__ __forceinline__ float bf2f(u16 h) {
    return __uint_as_float(((unsigned int)h) << 16);
}
// packed f32x2 -> bf16x2 (HW RNE), no builtin on gfx950 -> inline asm
__device__ __forceinline__ unsigned int cvt_pk_bf16(float a, float b) {
    unsigned int r;
    asm("v_cvt_pk_bf16_f32 %0, %1, %2" : "=v"(r) : "v"(a), "v"(b));
    return r;
}
__device__ __forceinline__ void st8(u16* p, short8 v) {
    u16x4 a, b;
    a[0]=(u16)v[0]; a[1]=(u16)v[1]; a[2]=(u16)v[2]; a[3]=(u16)v[3];
    b[0]=(u16)v[4]; b[1]=(u16)v[5]; b[2]=(u16)v[6]; b[3]=(u16)v[7];
    *(u16x4*)p = a; *(u16x4*)(p + 4) = b;
}
// async global->LDS, 16B/lane. LDS dest = wave-uniform base + lane*16 (m104);
// global src is per-lane (pre-swizzled for bank-conflict-free reads, m173).
__device__ __forceinline__ void gld16(const u16* g, u16* l) {
    __builtin_amdgcn_global_load_lds(
        (const __attribute__((address_space(1))) void*)g,
        (__attribute__((address_space(3))) void*)l, 16, 0, 0);
}

// ---------------------------------------------------------------- gdiag
__global__ void gdiag_kernel(const float* __restrict__ A,
                             const float* __restrict__ log_lambda,
                             float* __restrict__ gdiag) {
    int id = blockIdx.x * 256 + threadIdx.x;
    if (id >= NHEAD * HDIM) return;
    int h = id >> 6, d = id & 63;
    float s = 0.f;
#pragma unroll
    for (int i = 0; i < 16; ++i) {
        float a = A[(h * 16 + i) * HDIM + d];
        s += a * a;
    }
    gdiag[id] = (s + __expf(log_lambda[h])) * 1.4426950408889634f;
}

// ---------------------------------------------------------------- prep: fp32 -> bf16 hi/lo
__global__ void prep_split(const float* __restrict__ x,
                           const float* __restrict__ Wq, const float* __restrict__ Wk,
                           const float* __restrict__ Wv, const float* __restrict__ Wo,
                           u16* __restrict__ xh, u16* __restrict__ xl,
                           u16* __restrict__ wqh, u16* __restrict__ wql,
                           u16* __restrict__ wkh, u16* __restrict__ wkl,
                           u16* __restrict__ wvh, u16* __restrict__ woh) {
    int seg = blockIdx.y;
    int i = blockIdx.x * 256 + threadIdx.x;   // float4 index
    const float* src; u16* dh; u16* dl; int n4;
    if      (seg == 0) { src = x;  dh = xh;  dl = xl;      n4 = NROWS * D_MODEL / 4; }
    else if (seg == 1) { src = Wq; dh = wqh; dl = wql;     n4 = D_MODEL * D_MODEL / 4; }
    else if (seg == 2) { src = Wk; dh = wkh; dl = wkl;     n4 = D_MODEL * D_MODEL / 4; }
    else if (seg == 3) { src = Wv; dh = wvh; dl = nullptr; n4 = D_MODEL * D_MODEL / 4; }
    else               { src = Wo; dh = woh; dl = nullptr; n4 = D_MODEL * D_MODEL / 4; }
    if (i >= n4) return;
    float4 v = *(const float4*)&src[(size_t)i * 4];
    float vv[4] = {v.x, v.y, v.z, v.w};
    u16x4 hv, lv;
#pragma unroll
    for (int j = 0; j < 4; ++j) {
        u16 hb = f2bf(vv[j]);
        hv[j] = hb;
        lv[j] = f2bf(vv[j] - bf2f(hb));
    }
    *(u16x4*)&dh[(size_t)i * 4] = hv;
    if (dl) *(u16x4*)&dl[(size_t)i * 4] = lv;
}

// ---------------------------------------------------------------- MFMA NT GEMM (global_load_lds staging)
// out[r][c] = sum_k A[r][k]*W[c][k] + bias[c]; A,W in bf16 hi(/lo), fp32 acc.
// Staging: per wave, rows [w*32, w*32+32) of each tile via 2 global_load_lds insts
// (16 rows = 1024B each). LDS linear [128][32]; global src chunk pre-swizzled by GF.
template<int NP3>
__global__ __launch_bounds__(256)
void gemm_mfma(const u16* __restrict__ Ah, const u16* __restrict__ Al,
               const u16* __restrict__ BhA, const u16* __restrict__ BlA, const float* __restrict__ biasA,
               float* outfA, u16* auxhA, u16* auxlA, float* ksumA,
               const u16* __restrict__ BhB, const u16* __restrict__ BlB, const float* __restrict__ biasB,
               float* outfB, u16* auxhB, u16* auxlB, float* ksumB,
               int out_layout) {
    const int z = blockIdx.z;
    const u16* Bh = (z == 0) ? BhA : BhB;
    const u16* Bl = (z == 0) ? BlA : BlB;
    const float* bias = (z == 0) ? biasA : biasB;
    float* outf = (z == 0) ? outfA : outfB;
    u16* auxh   = (z == 0) ? auxhA : auxhB;
    u16* auxl   = (z == 0) ? auxlA : auxlB;
    float* ksump= (z == 0) ? ksumA : ksumB;

    __shared__ __align__(16) u16 As_h[128][32], Bs_h[128][32];
    __shared__ __align__(16) u16 As_l[NP3 ? 128 : 1][32], Bs_l[NP3 ? 128 : 1][32];

    const int tid = threadIdx.x;
    const int w = tid >> 6, lane = tid & 63, quad = lane >> 4, n16 = lane & 15;
    const int rBase = blockIdx.y * 128;
    const int cBase = blockIdx.x * 128;

    // staging geometry: lane covers row srow (16 rows/inst), chunk (lane&3) of LDS,
    // sourcing global chunk (lane&3)^GF(row) so that LDS[row][c''] = global chunk c''^GF(row).
    const int srow0 = w * 32 + (lane >> 2);
    const int srow1 = srow0 + 16;
    const int sc0 = ((lane & 3) ^ GF(srow0)) * 8;
    const int sc1 = ((lane & 3) ^ GF(srow1)) * 8;

    f32x4 acc[2][8] = {};

    for (int kt = 0; kt < D_MODEL; kt += 32) {
        gld16(&Ah[(size_t)(rBase + srow0) * D_MODEL + kt + sc0], &As_h[w * 32][0]);
        gld16(&Ah[(size_t)(rBase + srow1) * D_MODEL + kt + sc1], &As_h[w * 32 + 16][0]);
        gld16(&Bh[(size_t)(cBase + srow0) * D_MODEL + kt + sc0], &Bs_h[w * 32][0]);
        gld16(&Bh[(size_t)(cBase + srow1) * D_MODEL + kt + sc1], &Bs_h[w * 32 + 16][0]);
        if (NP3) {
            gld16(&Al[(size_t)(rBase + srow0) * D_MODEL + kt + sc0], &As_l[w * 32][0]);
            gld16(&Al[(size_t)(rBase + srow1) * D_MODEL + kt + sc1], &As_l[w * 32 + 16][0]);
            gld16(&Bl[(size_t)(cBase + srow0) * D_MODEL + kt + sc0], &Bs_l[w * 32][0]);
            gld16(&Bl[(size_t)(cBase + srow1) * D_MODEL + kt + sc1], &Bs_l[w * 32 + 16][0]);
        }
        __syncthreads();   // compiler drains vmcnt before barrier -> LDS ready

        short8 a_h[2], a_l[2];
#pragma unroll
        for (int mt = 0; mt < 2; ++mt) {
            const int row = w * 32 + mt * 16 + n16;
            const int cc = (quad ^ GF(row)) * 8;
            a_h[mt] = *(const short8*)&As_h[row][cc];
            if (NP3) a_l[mt] = *(const short8*)&As_l[NP3 ? row : 0][cc];
        }
#pragma unroll
        for (int nt = 0; nt < 8; ++nt) {
            const int row = nt * 16 + n16;
            const int cc = (quad ^ GF(row)) * 8;
            short8 b_h = *(const short8*)&Bs_h[row][cc];
            short8 b_l;
            if (NP3) b_l = *(const short8*)&Bs_l[NP3 ? row : 0][cc];
#pragma unroll
            for (int mt = 0; mt < 2; ++mt) {
                acc[mt][nt] = __builtin_amdgcn_mfma_f32_16x16x32_bf16(a_h[mt], b_h, acc[mt][nt], 0, 0, 0);
                if (NP3) {
                    acc[mt][nt] = __builtin_amdgcn_mfma_f32_16x16x32_bf16(a_h[mt], b_l, acc[mt][nt], 0, 0, 0);
                    acc[mt][nt] = __builtin_amdgcn_mfma_f32_16x16x32_bf16(a_l[mt], b_h, acc[mt][nt], 0, 0, 0);
                }
            }
        }
        __syncthreads();
    }

    // epilogue: C row = quad*4+reg (within 16x16 tile), col = n16
    float csum[8];
#pragma unroll
    for (int nt = 0; nt < 8; ++nt) csum[nt] = 0.f;
#pragma unroll
    for (int mt = 0; mt < 2; ++mt) {
#pragma unroll
        for (int nt = 0; nt < 8; ++nt) {
            int c = cBase + nt * 16 + n16;
            float bc = bias[c];
            int rb = rBase + w * 32 + mt * 16 + quad * 4;
#pragma unroll
            for (int reg = 0; reg < 4; ++reg) {
                float val = acc[mt][nt][reg] + bc;
                int rr = rb + reg;
                size_t idx = out_layout
                    ? ((size_t)(((rr >> 11) * NHEAD + (c >> 6)) * SEQ + (rr & (SEQ - 1)))) * HDIM + (c & 63)
                    : (size_t)rr * D_MODEL + c;
                if (outf) outf[idx] = val;
                if (auxh) {
                    u16 hb = f2bf(val);
                    auxh[idx] = hb;
                    if (auxl) auxl[idx] = f2bf(val - bf2f(hb));
                }
                csum[nt] += val;
            }
        }
    }
    if (ksump) {
#pragma unroll
        for (int nt = 0; nt < 8; ++nt) {
            float cs = csum[nt];
            cs += __shfl_xor(cs, 16);
            cs += __shfl_xor(cs, 32);
            if (quad == 0) {
                int c = cBase + nt * 16 + n16;
                int bb = rBase >> 11;
                atomicAdd(&ksump[(bb * NHEAD + (c >> 6)) * HDIM + (c & 63)], cs);
            }
        }
    }
}

// ---------------------------------------------------------------- v transpose: (b,h,t,hd) bf16 -> (b,h,hd,t) bf16
__global__ __launch_bounds__(256)
void vtrans_kernel(const u16* __restrict__ vh, u16* __restrict__ vT) {
    __shared__ u16 tile[64][72];
    const int tid = threadIdx.x;
    const int t0 = blockIdx.x * 64;
    const int bh = blockIdx.y;
    const u16* vp = vh + (size_t)bh * SEQ * HDIM;
#pragma unroll
    for (int s = 0; s < 2; ++s) {
        int id = s * 256 + tid;
        int row = id >> 3, c8 = (id & 7) * 8;
        st8(&tile[row][c8], *(const short8*)&vp[(size_t)(t0 + row) * HDIM + c8]);
    }
    __syncthreads();
#pragma unroll
    for (int s = 0; s < 2; ++s) {
        int id = s * 256 + tid;
        int d = id >> 3, t8 = (id & 7) * 8;
        short8 r;
#pragma unroll
        for (int i = 0; i < 8; ++i) r[i] = (short)tile[t8 + i][d];
        *(short8*)&vT[((size_t)bh * HDIM + d) * SEQ + t0 + t8] = r;
    }
}

// ---------------------------------------------------------------- flash attention (round-3 version, best measured)
// QBLK=128: 4 waves x 32 queries (2 fragments mt). K/V LDS double-buffered (one barrier
// per tile); XOR chunk swizzle. Swapped-operand QK^T; T13 defer-max; lane-local l.
__global__ __launch_bounds__(256, 2)
void flash_mfma(const float* __restrict__ q, const u16* __restrict__ kh,
                const u16* __restrict__ kl, const u16* __restrict__ vT,
                const float* __restrict__ ksum, const float* __restrict__ gdiag,
                u16* __restrict__ o) {
    __shared__ __align__(16) u16 khs[2][64][64], kls[2][64][64], vTs[2][64][64];
    __shared__ __align__(16) u16 ps[4][32][64];

    const int tid = threadIdx.x;
    const int w = tid >> 6, lane = tid & 63, quad = lane >> 4, n16 = lane & 15;
    const int t0 = blockIdx.x * 128;
    const int h = blockIdx.y, b = blockIdx.z;
    const size_t bh = (size_t)b * NHEAD + h;
    const float* qp = q + bh * SEQ * HDIM;
    const u16* khp = kh + bh * SEQ * HDIM;
    const u16* klp = kl + bh * SEQ * HDIM;
    const u16* vtp = vT + bh * HDIM * SEQ;

    // Sg fragments: sg*[mt][kc][j], d = kc*32 + quad*8 + j, query = t0+w*32+mt*16+n16
    short8 sgh[2][2], sgl[2][2];
#pragma unroll
    for (int mt = 0; mt < 2; ++mt) {
        int qrow = t0 + w * 32 + mt * 16 + n16;
#pragma unroll
        for (int kc = 0; kc < 2; ++kc) {
            int d0 = kc * 32 + quad * 8;
            float4 q0 = *(const float4*)&qp[(size_t)qrow * HDIM + d0];
            float4 q1 = *(const float4*)&qp[(size_t)qrow * HDIM + d0 + 4];
            float4 k0 = *(const float4*)&ksum[bh * HDIM + d0];
            float4 k1 = *(const float4*)&ksum[bh * HDIM + d0 + 4];
            float4 g0 = *(const float4*)&gdiag[(size_t)h * HDIM + d0];
            float4 g1 = *(const float4*)&gdiag[(size_t)h * HDIM + d0 + 4];
            float sg[8];
            sg[0] = (2048.f * q0.x - k0.x) * g0.x; sg[1] = (2048.f * q0.y - k0.y) * g0.y;
            sg[2] = (2048.f * q0.z - k0.z) * g0.z; sg[3] = (2048.f * q0.w - k0.w) * g0.w;
            sg[4] = (2048.f * q1.x - k1.x) * g1.x; sg[5] = (2048.f * q1.y - k1.y) * g1.y;
            sg[6] = (2048.f * q1.z - k1.z) * g1.z; sg[7] = (2048.f * q1.w - k1.w) * g1.w;
#pragma unroll
            for (int j = 0; j < 8; ++j) {
                u16 hb = f2bf(sg[j]);
                sgh[mt][kc][j] = (short)hb;
                sgl[mt][kc][j] = (short)f2bf(sg[j] - bf2f(hb));
            }
        }
    }

    f32x4 oaccv[2][4] = {};
    float m_n[2] = {-INFINITY, -INFINITY};
    float l_n[2] = {0.f, 0.f};     // lane-local partial sums; reduced in epilogue

    const int srow = tid >> 3;            // 0..31
    const int sc   = tid & 7;             // chunk
    const int scg  = sc * 8;              // global u16 col
    const int scl  = SWZ(srow, sc);       // LDS u16 col

    // prologue: load+store tile j0=0 into buffer 0
    short8 rk0h = *(const short8*)&khp[(size_t)srow * HDIM + scg];
    short8 rk1h = *(const short8*)&khp[(size_t)(srow + 32) * HDIM + scg];
    short8 rk0l = *(const short8*)&klp[(size_t)srow * HDIM + scg];
    short8 rk1l = *(const short8*)&klp[(size_t)(srow + 32) * HDIM + scg];
    short8 rv0  = *(const short8*)&vtp[(size_t)srow * SEQ + scg];
    short8 rv1  = *(const short8*)&vtp[(size_t)(srow + 32) * SEQ + scg];
    *(short8*)&khs[0][srow][scl] = rk0h;  *(short8*)&khs[0][srow + 32][scl] = rk1h;
    *(short8*)&kls[0][srow][scl] = rk0l;  *(short8*)&kls[0][srow + 32][scl] = rk1l;
    *(short8*)&vTs[0][srow][scl] = rv0;   *(short8*)&vTs[0][srow + 32][scl] = rv1;

    int cur = 0;
    for (int j0 = 0; j0 < SEQ; j0 += 64, cur ^= 1) {
        __syncthreads();   // buf[cur] staged; buf[cur^1] free to overwrite
        const int jn = j0 + 64;
        const bool pf = (jn < SEQ);
        if (pf) {
            rk0h = *(const short8*)&khp[(size_t)(jn + srow) * HDIM + scg];
            rk1h = *(const short8*)&khp[(size_t)(jn + srow + 32) * HDIM + scg];
            rk0l = *(const short8*)&klp[(size_t)(jn + srow) * HDIM + scg];
            rk1l = *(const short8*)&klp[(size_t)(jn + srow + 32) * HDIM + scg];
            rv0  = *(const short8*)&vtp[(size_t)srow * SEQ + jn + scg];
            rv1  = *(const short8*)&vtp[(size_t)(srow + 32) * SEQ + jn + scg];
        }

        // QK^T: K fragments read ONCE, used by both mt. 3-pass split bf16.
        f32x4 lgT[2][4] = {};
#pragma unroll
        for (int kc = 0; kc < 2; ++kc) {
#pragma unroll
            for (int nt = 0; nt < 4; ++nt) {
                const int row = nt * 16 + n16;
                const int cc = SWZ(row, kc * 4 + quad);
                short8 b_h = *(const short8*)&khs[cur][row][cc];
                short8 b_l = *(const short8*)&kls[cur][row][cc];
#pragma unroll
                for (int mt = 0; mt < 2; ++mt) {
                    lgT[mt][nt] = __builtin_amdgcn_mfma_f32_16x16x32_bf16(b_h, sgh[mt][kc], lgT[mt][nt], 0, 0, 0);
                    lgT[mt][nt] = __builtin_amdgcn_mfma_f32_16x16x32_bf16(b_l, sgh[mt][kc], lgT[mt][nt], 0, 0, 0);
                    lgT[mt][nt] = __builtin_amdgcn_mfma_f32_16x16x32_bf16(b_h, sgl[mt][kc], lgT[mt][nt], 0, 0, 0);
                }
            }
        }

        // tile max per query fragment
        float mx[2];
#pragma unroll
        for (int mt = 0; mt < 2; ++mt) {
            float m0 = fmaxf(fmaxf(lgT[mt][0][0], lgT[mt][0][1]), lgT[mt][0][2]);
            m0 = fmaxf(fmaxf(m0, lgT[mt][0][3]), lgT[mt][1][0]);
            m0 = fmaxf(fmaxf(m0, lgT[mt][1][1]), lgT[mt][1][2]);
            m0 = fmaxf(fmaxf(m0, lgT[mt][1][3]), lgT[mt][2][0]);
            m0 = fmaxf(fmaxf(m0, lgT[mt][2][1]), lgT[mt][2][2]);
            m0 = fmaxf(fmaxf(m0, lgT[mt][2][3]), lgT[mt][3][0]);
            m0 = fmaxf(fmaxf(m0, lgT[mt][3][1]), lgT[mt][3][2]);
            m0 = fmaxf(m0, lgT[mt][3][3]);
            m0 = fmaxf(m0, __shfl_xor(m0, 16));
            mx[mt] = fmaxf(m0, __shfl_xor(m0, 32));
        }

        // T13 defer-max
        const float need = fmaxf(mx[0] - m_n[0], mx[1] - m_n[1]);
        if (!__all(need <= 8.f)) {
#pragma unroll
            for (int mt = 0; mt < 2; ++mt) {
                const float mn = fmaxf(m_n[mt], mx[mt]);
                const float alpha = exp2f(m_n[mt] - mn);
                m_n[mt] = mn;
                l_n[mt] *= alpha;
                const float a0 = __shfl(alpha, quad * 4 + 0);
                const float a1 = __shfl(alpha, quad * 4 + 1);
                const float a2 = __shfl(alpha, quad * 4 + 2);
                const float a3 = __shfl(alpha, quad * 4 + 3);
#pragma unroll
                for (int nt = 0; nt < 4; ++nt) {
                    oaccv[mt][nt][0] *= a0; oaccv[mt][nt][1] *= a1;
                    oaccv[mt][nt][2] *= a2; oaccv[mt][nt][3] *= a3;
                }
            }
        }

        // P = exp2(lg - m), packed bf16 to per-wave LDS; lane-local psum
#pragma unroll
        for (int mt = 0; mt < 2; ++mt) {
            const int prow = mt * 16 + n16;
            const float mn = m_n[mt];
            float psum = 0.f;
#pragma unroll
            for (int nt = 0; nt < 4; ++nt) {
#pragma unroll
                for (int r = 0; r < 4; ++r) lgT[mt][nt][r] = exp2f(lgT[mt][nt][r] - mn);
                u32x2 pk;
                pk[0] = cvt_pk_bf16(lgT[mt][nt][0], lgT[mt][nt][1]);
                pk[1] = cvt_pk_bf16(lgT[mt][nt][2], lgT[mt][nt][3]);
                *(u32x2*)&ps[w][prow][SWZ(prow, nt * 2 + (quad >> 1)) + (quad & 1) * 4] = pk;
                psum += (lgT[mt][nt][0] + lgT[mt][nt][1]) + (lgT[mt][nt][2] + lgT[mt][nt][3]);
            }
            l_n[mt] += psum;
        }

        // PV: V fragments read ONCE, used by both mt.
        short8 pa[2][2];
#pragma unroll
        for (int mt = 0; mt < 2; ++mt) {
            const int prow = mt * 16 + n16;
            pa[mt][0] = *(const short8*)&ps[w][prow][SWZ(prow, quad)];
            pa[mt][1] = *(const short8*)&ps[w][prow][SWZ(prow, quad + 4)];
        }
#pragma unroll
        for (int nt = 0; nt < 4; ++nt) {
            const int row = nt * 16 + n16;
            short8 v0 = *(const short8*)&vTs[cur][row][SWZ(row, quad)];
            short8 v1 = *(const short8*)&vTs[cur][row][SWZ(row, quad + 4)];
#pragma unroll
            for (int mt = 0; mt < 2; ++mt) {
                oaccv[mt][nt] = __builtin_amdgcn_mfma_f32_16x16x32_bf16(pa[mt][0], v0, oaccv[mt][nt], 0, 0, 0);
                oaccv[mt][nt] = __builtin_amdgcn_mfma_f32_16x16x32_bf16(pa[mt][1], v1, oaccv[mt][nt], 0, 0, 0);
            }
        }

        // stage-write next tile into idle buffer (next-iter top barrier syncs)
        if (pf) {
            const int nx = cur ^ 1;
            *(short8*)&khs[nx][srow][scl] = rk0h;  *(short8*)&khs[nx][srow + 32][scl] = rk1h;
            *(short8*)&kls[nx][srow][scl] = rk0l;  *(short8*)&kls[nx][srow + 32][scl] = rk1l;
            *(short8*)&vTs[nx][srow][scl] = rv0;   *(short8*)&vTs[nx][srow + 32][scl] = rv1;
        }
    }

    // epilogue: reduce lane-local l, write o_hi bf16, row-major (b, t, h*64+d)
#pragma unroll
    for (int mt = 0; mt < 2; ++mt) {
        float l = l_n[mt];
        l += __shfl_xor(l, 16);
        l += __shfl_xor(l, 32);
        l_n[mt] = l;
    }
#pragma unroll
    for (int mt = 0; mt < 2; ++mt) {
#pragma unroll
        for (int r = 0; r < 4; ++r) {
            float lr = __shfl(l_n[mt], quad * 4 + r);
            float inv = 1.f / lr;
            int t = t0 + w * 32 + mt * 16 + quad * 4 + r;
#pragma unroll
            for (int nt = 0; nt < 4; ++nt) {
                int d = nt * 16 + n16;
                o[((size_t)(b * SEQ + t)) * D_MODEL + h * HDIM + d] = f2bf(oaccv[mt][nt][r] * inv);
            }
        }
    }
}

// ---------------------------------------------------------------- launcher
extern "C" void kernel_launch(void* const* d_in, const int* in_sizes, int n_in,
                              void* d_out, int out_size, void* d_ws, size_t ws_size,
                              hipStream_t stream) {
    const float* x  = (const float*)d_in[0];
    const float* Wq = (const float*)d_in[1];
    const float* bq = (const float*)d_in[2];
    const float* Wk = (const float*)d_in[3];
    const float* bk = (const float*)d_in[4];
    const float* Wv = (const float*)d_in[5];
    const float* bv = (const float*)d_in[6];
    const float* Wo = (const float*)d_in[7];
    const float* bo = (const float*)d_in[8];
    const float* A  = (const float*)d_in[9];
    const float* ll = (const float*)d_in[10];
    float* out = (float*)d_out;

    const size_t NQKV = (size_t)NROWS * D_MODEL;   // 4,194,304
    const size_t NW = (size_t)D_MODEL * D_MODEL;   // 1,048,576
    char* base = (char*)d_ws;
    float* q_ws = (float*)base;            base += NQKV * 4;
    u16* xh  = (u16*)base;                 base += NQKV * 2;   // reused as o_hi after QKV
    u16* xl  = (u16*)base;                 base += NQKV * 2;   // reused as vT after QKV
    u16* khw = (u16*)base;                 base += NQKV * 2;
    u16* klw = (u16*)base;                 base += NQKV * 2;
    u16* vhw = (u16*)base;                 base += NQKV * 2;
    u16* wqh = (u16*)base;                 base += NW * 2;
    u16* wql = (u16*)base;                 base += NW * 2;
    u16* wkh = (u16*)base;                 base += NW * 2;
    u16* wkl = (u16*)base;                 base += NW * 2;
    u16* wvh = (u16*)base;                 base += NW * 2;
    u16* woh = (u16*)base;                 base += NW * 2;
    float* gd_ws   = (float*)base;         base += NHEAD * HDIM * 4;
    float* ksum_ws = (float*)base;         base += BATCH * NHEAD * HDIM * 4;

    hipMemsetAsync(ksum_ws, 0, BATCH * NHEAD * HDIM * sizeof(float), stream);

    prep_split<<<dim3(4096, 5), 256, 0, stream>>>(x, Wq, Wk, Wv, Wo,
                                                  xh, xl, wqh, wql, wkh, wkl, wvh, woh);
    gdiag_kernel<<<4, 256, 0, stream>>>(A, ll, gd_ws);

    // Q (z=0) + K (z=1): 3-pass split-bf16; K writes k_hi/k_lo + ksum atomics
    gemm_mfma<1><<<dim3(8, 32, 2), 256, 0, stream>>>(
        xh, xl,
        wqh, wql, bq, q_ws, nullptr, nullptr, nullptr,
        wkh, wkl, bk, nullptr, khw, klw, ksum_ws,
        1);
    // V: 1-pass bf16, writes v_hi bf16 only
    gemm_mfma<0><<<dim3(8, 32, 1), 256, 0, stream>>>(
        xh, nullptr,
        wvh, nullptr, bv, nullptr, vhw, nullptr, nullptr,
        wvh, nullptr, bv, nullptr, vhw, nullptr, nullptr,
        1);

    u16* vTw = xl;   // alias: x_lo dead after QKV GEMMs
    u16* ohw = xh;   // alias: x_hi dead after QKV GEMMs
    vtrans_kernel<<<dim3(SEQ / 64, BATCH * NHEAD), 256, 0, stream>>>(vhw, vTw);

    flash_mfma<<<dim3(SEQ / 128, NHEAD, BATCH), 256, 0, stream>>>(
        q_ws, khw, klw, vTw, ksum_ws, gd_ws, ohw);

    // out-proj: 1-pass bf16, row-major fp32 output
    gemm_mfma<0><<<dim3(8, 32, 1), 256, 0, stream>>>(
        ohw, nullptr,
        woh, nullptr, bo, out, nullptr, nullptr, nullptr,
        woh, nullptr, bo, out, nullptr, nullptr, nullptr,
        0);
}

// Round 10
// 303.104 us; speedup vs baseline: 1.1726x; 1.0146x over previous
//
#include <hip/hip_runtime.h>
#include <math.h>

#define D_MODEL 1024
#define NHEAD   16
#define HDIM    64
#define SEQ     2048
#define BATCH   2
#define NROWS   (BATCH*SEQ)   // 4096

typedef unsigned short u16;
typedef __attribute__((ext_vector_type(4))) unsigned short u16x4;
typedef __attribute__((ext_vector_type(8))) short short8;
typedef __attribute__((ext_vector_type(4))) float f32x4;
typedef __attribute__((ext_vector_type(2))) unsigned int u32x2;

// Flash LDS swizzle: 16B chunk c of row r lives at chunk c ^ (r & 7) (8 chunks/row).
#define SWZ(row, c) (((c) ^ ((row) & 7)) * 8)
// GEMM LDS swizzle for [*][32] bf16 tiles (4 chunks/row) — r9-verified.
#define GF(row) ((((row) + ((row) >> 2))) & 3)

// ---- bf16 helpers (RNE) ----
__device__ __forceinline__ u16 f2bf(float x) {
    unsigned int u = __float_as_uint(x);
    u += 0x7fffu + ((u >> 16) & 1u);
    return (u16)(u >> 16);
}
__device__ __forceinline__ float bf2f(u16 h) {
    return __uint_as_float(((unsigned int)h) << 16);
}
// packed f32x2 -> bf16x2 (HW RNE), no builtin on gfx950 -> inline asm
__device__ __forceinline__ unsigned int cvt_pk_bf16(float a, float b) {
    unsigned int r;
    asm("v_cvt_pk_bf16_f32 %0, %1, %2" : "=v"(r) : "v"(a), "v"(b));
    return r;
}
__device__ __forceinline__ void st8(u16* p, short8 v) {
    u16x4 a, b;
    a[0]=(u16)v[0]; a[1]=(u16)v[1]; a[2]=(u16)v[2]; a[3]=(u16)v[3];
    b[0]=(u16)v[4]; b[1]=(u16)v[5]; b[2]=(u16)v[6]; b[3]=(u16)v[7];
    *(u16x4*)p = a; *(u16x4*)(p + 4) = b;
}
// async global->LDS, 16B/lane. LDS dest = wave-uniform base + lane*16 (m104);
// global src is per-lane (pre-swizzled for bank-conflict-free reads, m173).
__device__ __forceinline__ void gld16(const u16* g, u16* l) {
    __builtin_amdgcn_global_load_lds(
        (const __attribute__((address_space(1))) void*)g,
        (__attribute__((address_space(3))) void*)l, 16, 0, 0);
}

// ---------------------------------------------------------------- gdiag
__global__ void gdiag_kernel(const float* __restrict__ A,
                             const float* __restrict__ log_lambda,
                             float* __restrict__ gdiag) {
    int id = blockIdx.x * 256 + threadIdx.x;
    if (id >= NHEAD * HDIM) return;
    int h = id >> 6, d = id & 63;
    float s = 0.f;
#pragma unroll
    for (int i = 0; i < 16; ++i) {
        float a = A[(h * 16 + i) * HDIM + d];
        s += a * a;
    }
    gdiag[id] = (s + __expf(log_lambda[h])) * 1.4426950408889634f;
}

// ---------------------------------------------------------------- prep: fp32 -> bf16 hi/lo
__global__ void prep_split(const float* __restrict__ x,
                           const float* __restrict__ Wq, const float* __restrict__ Wk,
                           const float* __restrict__ Wv, const float* __restrict__ Wo,
                           u16* __restrict__ xh, u16* __restrict__ xl,
                           u16* __restrict__ wqh, u16* __restrict__ wql,
                           u16* __restrict__ wkh, u16* __restrict__ wkl,
                           u16* __restrict__ wvh, u16* __restrict__ woh) {
    int seg = blockIdx.y;
    int i = blockIdx.x * 256 + threadIdx.x;   // float4 index
    const float* src; u16* dh; u16* dl; int n4;
    if      (seg == 0) { src = x;  dh = xh;  dl = xl;      n4 = NROWS * D_MODEL / 4; }
    else if (seg == 1) { src = Wq; dh = wqh; dl = wql;     n4 = D_MODEL * D_MODEL / 4; }
    else if (seg == 2) { src = Wk; dh = wkh; dl = wkl;     n4 = D_MODEL * D_MODEL / 4; }
    else if (seg == 3) { src = Wv; dh = wvh; dl = nullptr; n4 = D_MODEL * D_MODEL / 4; }
    else               { src = Wo; dh = woh; dl = nullptr; n4 = D_MODEL * D_MODEL / 4; }
    if (i >= n4) return;
    float4 v = *(const float4*)&src[(size_t)i * 4];
    float vv[4] = {v.x, v.y, v.z, v.w};
    u16x4 hv, lv;
#pragma unroll
    for (int j = 0; j < 4; ++j) {
        u16 hb = f2bf(vv[j]);
        hv[j] = hb;
        lv[j] = f2bf(vv[j] - bf2f(hb));
    }
    *(u16x4*)&dh[(size_t)i * 4] = hv;
    if (dl) *(u16x4*)&dl[(size_t)i * 4] = lv;
}

// ---------------------------------------------------------------- MFMA NT GEMM (occupancy re-geometry)
// out[r][c] = sum_k A[r][k]*W[c][k] + bias[c]; A,W in bf16 hi(/lo), fp32 acc.
// Tile 128x64, BK=32, 512 threads (8 waves), wave = 16 rows x 64 cols -> acc 16 AGPR.
// Total regs ~100 -> 128 bucket -> 4 waves/SIMD, 2 blocks/CU = 16 waves/CU
// (r9's 128x128/4-wave had 64 AGPR -> 164 total -> 2 waves/SIMD; V/O grids 1 block/CU).
// Staging: r9-verified global_load_lds(16B) with GF pre-swizzled source chunks.
template<int NP3>
__global__ __launch_bounds__(512, 4)
void gemm_mfma(const u16* __restrict__ Ah, const u16* __restrict__ Al,
               const u16* __restrict__ BhA, const u16* __restrict__ BlA, const float* __restrict__ biasA,
               float* outfA, u16* auxhA, u16* auxlA, float* ksumA,
               const u16* __restrict__ BhB, const u16* __restrict__ BlB, const float* __restrict__ biasB,
               float* outfB, u16* auxhB, u16* auxlB, float* ksumB,
               int out_layout) {
    const int z = blockIdx.z;
    const u16* Bh = (z == 0) ? BhA : BhB;
    const u16* Bl = (z == 0) ? BlA : BlB;
    const float* bias = (z == 0) ? biasA : biasB;
    float* outf = (z == 0) ? outfA : outfB;
    u16* auxh   = (z == 0) ? auxhA : auxhB;
    u16* auxl   = (z == 0) ? auxlA : auxlB;
    float* ksump= (z == 0) ? ksumA : ksumB;

    __shared__ __align__(16) u16 As_h[128][32], Bs_h[64][32];
    __shared__ __align__(16) u16 As_l[NP3 ? 128 : 1][32], Bs_l[NP3 ? 64 : 1][32];

    const int tid = threadIdx.x;
    const int w = tid >> 6, lane = tid & 63, quad = lane >> 4, n16 = lane & 15;
    const int rBase = blockIdx.y * 128;
    const int cBase = blockIdx.x * 64;

    // staging geometry: lane covers row base+(lane>>2), chunk (lane&3) of LDS,
    // sourcing global chunk (lane&3)^GF(row) so LDS[row][c''] = global chunk c''^GF(row).
    const int lrow = lane >> 2;          // 0..15
    const int lch  = lane & 3;
    const int arow = w * 16 + lrow;      // A rows for this wave
    const int asc  = ((lch ^ GF(arow)) * 8);
    const int brow = (w & 3) * 16 + lrow;  // B rows (waves 0-3: B_h; waves 4-7: B_l)
    const int bsc  = ((lch ^ GF(brow)) * 8);

    f32x4 acc[4] = {};

    for (int kt = 0; kt < D_MODEL; kt += 32) {
        gld16(&Ah[(size_t)(rBase + arow) * D_MODEL + kt + asc], &As_h[w * 16][0]);
        if (NP3) gld16(&Al[(size_t)(rBase + arow) * D_MODEL + kt + asc], &As_l[w * 16][0]);
        if (w < 4) {
            gld16(&Bh[(size_t)(cBase + brow) * D_MODEL + kt + bsc], &Bs_h[(w & 3) * 16][0]);
        } else if (NP3) {
            gld16(&Bl[(size_t)(cBase + brow) * D_MODEL + kt + bsc], &Bs_l[NP3 ? (w & 3) * 16 : 0][0]);
        }
        __syncthreads();   // compiler drains vmcnt before barrier -> LDS ready

        short8 a_h, a_l;
        {
            const int row = w * 16 + n16;
            const int cc = (quad ^ GF(row)) * 8;
            a_h = *(const short8*)&As_h[row][cc];
            if (NP3) a_l = *(const short8*)&As_l[NP3 ? row : 0][cc];
        }
#pragma unroll
        for (int nt = 0; nt < 4; ++nt) {
            const int row = nt * 16 + n16;
            const int cc = (quad ^ GF(row)) * 8;
            short8 b_h = *(const short8*)&Bs_h[row][cc];
            short8 b_l;
            if (NP3) b_l = *(const short8*)&Bs_l[NP3 ? row : 0][cc];
            acc[nt] = __builtin_amdgcn_mfma_f32_16x16x32_bf16(a_h, b_h, acc[nt], 0, 0, 0);
            if (NP3) {
                acc[nt] = __builtin_amdgcn_mfma_f32_16x16x32_bf16(a_h, b_l, acc[nt], 0, 0, 0);
                acc[nt] = __builtin_amdgcn_mfma_f32_16x16x32_bf16(a_l, b_h, acc[nt], 0, 0, 0);
            }
        }
        __syncthreads();
    }

    // epilogue: C row = quad*4+reg (within 16x16 tile), col = n16
    float csum[4];
#pragma unroll
    for (int nt = 0; nt < 4; ++nt) csum[nt] = 0.f;
#pragma unroll
    for (int nt = 0; nt < 4; ++nt) {
        int c = cBase + nt * 16 + n16;
        float bc = bias[c];
        int rb = rBase + w * 16 + quad * 4;
#pragma unroll
        for (int reg = 0; reg < 4; ++reg) {
            float val = acc[nt][reg] + bc;
            int rr = rb + reg;
            size_t idx = out_layout
                ? ((size_t)(((rr >> 11) * NHEAD + (c >> 6)) * SEQ + (rr & (SEQ - 1)))) * HDIM + (c & 63)
                : (size_t)rr * D_MODEL + c;
            if (outf) outf[idx] = val;
            if (auxh) {
                u16 hb = f2bf(val);
                auxh[idx] = hb;
                if (auxl) auxl[idx] = f2bf(val - bf2f(hb));
            }
            csum[nt] += val;
        }
    }
    if (ksump) {
#pragma unroll
        for (int nt = 0; nt < 4; ++nt) {
            float cs = csum[nt];
            cs += __shfl_xor(cs, 16);
            cs += __shfl_xor(cs, 32);
            if (quad == 0) {
                int c = cBase + nt * 16 + n16;
                int bb = rBase >> 11;
                atomicAdd(&ksump[(bb * NHEAD + (c >> 6)) * HDIM + (c & 63)], cs);
            }
        }
    }
}

// ---------------------------------------------------------------- v transpose: (b,h,t,hd) bf16 -> (b,h,hd,t) bf16
__global__ __launch_bounds__(256)
void vtrans_kernel(const u16* __restrict__ vh, u16* __restrict__ vT) {
    __shared__ u16 tile[64][72];
    const int tid = threadIdx.x;
    const int t0 = blockIdx.x * 64;
    const int bh = blockIdx.y;
    const u16* vp = vh + (size_t)bh * SEQ * HDIM;
#pragma unroll
    for (int s = 0; s < 2; ++s) {
        int id = s * 256 + tid;
        int row = id >> 3, c8 = (id & 7) * 8;
        st8(&tile[row][c8], *(const short8*)&vp[(size_t)(t0 + row) * HDIM + c8]);
    }
    __syncthreads();
#pragma unroll
    for (int s = 0; s < 2; ++s) {
        int id = s * 256 + tid;
        int d = id >> 3, t8 = (id & 7) * 8;
        short8 r;
#pragma unroll
        for (int i = 0; i < 8; ++i) r[i] = (short)tile[t8 + i][d];
        *(short8*)&vT[((size_t)bh * HDIM + d) * SEQ + t0 + t8] = r;
    }
}

// ---------------------------------------------------------------- flash attention (round-3 version, best measured)
// QBLK=128: 4 waves x 32 queries (2 fragments mt). K/V LDS double-buffered (one barrier
// per tile); XOR chunk swizzle. Swapped-operand QK^T; T13 defer-max; lane-local l.
__global__ __launch_bounds__(256, 2)
void flash_mfma(const float* __restrict__ q, const u16* __restrict__ kh,
                const u16* __restrict__ kl, const u16* __restrict__ vT,
                const float* __restrict__ ksum, const float* __restrict__ gdiag,
                u16* __restrict__ o) {
    __shared__ __align__(16) u16 khs[2][64][64], kls[2][64][64], vTs[2][64][64];
    __shared__ __align__(16) u16 ps[4][32][64];

    const int tid = threadIdx.x;
    const int w = tid >> 6, lane = tid & 63, quad = lane >> 4, n16 = lane & 15;
    const int t0 = blockIdx.x * 128;
    const int h = blockIdx.y, b = blockIdx.z;
    const size_t bh = (size_t)b * NHEAD + h;
    const float* qp = q + bh * SEQ * HDIM;
    const u16* khp = kh + bh * SEQ * HDIM;
    const u16* klp = kl + bh * SEQ * HDIM;
    const u16* vtp = vT + bh * HDIM * SEQ;

    // Sg fragments: sg*[mt][kc][j], d = kc*32 + quad*8 + j, query = t0+w*32+mt*16+n16
    short8 sgh[2][2], sgl[2][2];
#pragma unroll
    for (int mt = 0; mt < 2; ++mt) {
        int qrow = t0 + w * 32 + mt * 16 + n16;
#pragma unroll
        for (int kc = 0; kc < 2; ++kc) {
            int d0 = kc * 32 + quad * 8;
            float4 q0 = *(const float4*)&qp[(size_t)qrow * HDIM + d0];
            float4 q1 = *(const float4*)&qp[(size_t)qrow * HDIM + d0 + 4];
            float4 k0 = *(const float4*)&ksum[bh * HDIM + d0];
            float4 k1 = *(const float4*)&ksum[bh * HDIM + d0 + 4];
            float4 g0 = *(const float4*)&gdiag[(size_t)h * HDIM + d0];
            float4 g1 = *(const float4*)&gdiag[(size_t)h * HDIM + d0 + 4];
            float sg[8];
            sg[0] = (2048.f * q0.x - k0.x) * g0.x; sg[1] = (2048.f * q0.y - k0.y) * g0.y;
            sg[2] = (2048.f * q0.z - k0.z) * g0.z; sg[3] = (2048.f * q0.w - k0.w) * g0.w;
            sg[4] = (2048.f * q1.x - k1.x) * g1.x; sg[5] = (2048.f * q1.y - k1.y) * g1.y;
            sg[6] = (2048.f * q1.z - k1.z) * g1.z; sg[7] = (2048.f * q1.w - k1.w) * g1.w;
#pragma unroll
            for (int j = 0; j < 8; ++j) {
                u16 hb = f2bf(sg[j]);
                sgh[mt][kc][j] = (short)hb;
                sgl[mt][kc][j] = (short)f2bf(sg[j] - bf2f(hb));
            }
        }
    }

    f32x4 oaccv[2][4] = {};
    float m_n[2] = {-INFINITY, -INFINITY};
    float l_n[2] = {0.f, 0.f};     // lane-local partial sums; reduced in epilogue

    const int srow = tid >> 3;            // 0..31
    const int sc   = tid & 7;             // chunk
    const int scg  = sc * 8;              // global u16 col
    const int scl  = SWZ(srow, sc);       // LDS u16 col

    // prologue: load+store tile j0=0 into buffer 0
    short8 rk0h = *(const short8*)&khp[(size_t)srow * HDIM + scg];
    short8 rk1h = *(const short8*)&khp[(size_t)(srow + 32) * HDIM + scg];
    short8 rk0l = *(const short8*)&klp[(size_t)srow * HDIM + scg];
    short8 rk1l = *(const short8*)&klp[(size_t)(srow + 32) * HDIM + scg];
    short8 rv0  = *(const short8*)&vtp[(size_t)srow * SEQ + scg];
    short8 rv1  = *(const short8*)&vtp[(size_t)(srow + 32) * SEQ + scg];
    *(short8*)&khs[0][srow][scl] = rk0h;  *(short8*)&khs[0][srow + 32][scl] = rk1h;
    *(short8*)&kls[0][srow][scl] = rk0l;  *(short8*)&kls[0][srow + 32][scl] = rk1l;
    *(short8*)&vTs[0][srow][scl] = rv0;   *(short8*)&vTs[0][srow + 32][scl] = rv1;

    int cur = 0;
    for (int j0 = 0; j0 < SEQ; j0 += 64, cur ^= 1) {
        __syncthreads();   // buf[cur] staged; buf[cur^1] free to overwrite
        const int jn = j0 + 64;
        const bool pf = (jn < SEQ);
        if (pf) {
            rk0h = *(const short8*)&khp[(size_t)(jn + srow) * HDIM + scg];
            rk1h = *(const short8*)&khp[(size_t)(jn + srow + 32) * HDIM + scg];
            rk0l = *(const short8*)&klp[(size_t)(jn + srow) * HDIM + scg];
            rk1l = *(const short8*)&klp[(size_t)(jn + srow + 32) * HDIM + scg];
            rv0  = *(const short8*)&vtp[(size_t)srow * SEQ + jn + scg];
            rv1  = *(const short8*)&vtp[(size_t)(srow + 32) * SEQ + jn + scg];
        }

        // QK^T: K fragments read ONCE, used by both mt. 3-pass split bf16.
        f32x4 lgT[2][4] = {};
#pragma unroll
        for (int kc = 0; kc < 2; ++kc) {
#pragma unroll
            for (int nt = 0; nt < 4; ++nt) {
                const int row = nt * 16 + n16;
                const int cc = SWZ(row, kc * 4 + quad);
                short8 b_h = *(const short8*)&khs[cur][row][cc];
                short8 b_l = *(const short8*)&kls[cur][row][cc];
#pragma unroll
                for (int mt = 0; mt < 2; ++mt) {
                    lgT[mt][nt] = __builtin_amdgcn_mfma_f32_16x16x32_bf16(b_h, sgh[mt][kc], lgT[mt][nt], 0, 0, 0);
                    lgT[mt][nt] = __builtin_amdgcn_mfma_f32_16x16x32_bf16(b_l, sgh[mt][kc], lgT[mt][nt], 0, 0, 0);
                    lgT[mt][nt] = __builtin_amdgcn_mfma_f32_16x16x32_bf16(b_h, sgl[mt][kc], lgT[mt][nt], 0, 0, 0);
                }
            }
        }

        // tile max per query fragment
        float mx[2];
#pragma unroll
        for (int mt = 0; mt < 2; ++mt) {
            float m0 = fmaxf(fmaxf(lgT[mt][0][0], lgT[mt][0][1]), lgT[mt][0][2]);
            m0 = fmaxf(fmaxf(m0, lgT[mt][0][3]), lgT[mt][1][0]);
            m0 = fmaxf(fmaxf(m0, lgT[mt][1][1]), lgT[mt][1][2]);
            m0 = fmaxf(fmaxf(m0, lgT[mt][1][3]), lgT[mt][2][0]);
            m0 = fmaxf(fmaxf(m0, lgT[mt][2][1]), lgT[mt][2][2]);
            m0 = fmaxf(fmaxf(m0, lgT[mt][2][3]), lgT[mt][3][0]);
            m0 = fmaxf(fmaxf(m0, lgT[mt][3][1]), lgT[mt][3][2]);
            m0 = fmaxf(m0, lgT[mt][3][3]);
            m0 = fmaxf(m0, __shfl_xor(m0, 16));
            mx[mt] = fmaxf(m0, __shfl_xor(m0, 32));
        }

        // T13 defer-max
        const float need = fmaxf(mx[0] - m_n[0], mx[1] - m_n[1]);
        if (!__all(need <= 8.f)) {
#pragma unroll
            for (int mt = 0; mt < 2; ++mt) {
                const float mn = fmaxf(m_n[mt], mx[mt]);
                const float alpha = exp2f(m_n[mt] - mn);
                m_n[mt] = mn;
                l_n[mt] *= alpha;
                const float a0 = __shfl(alpha, quad * 4 + 0);
                const float a1 = __shfl(alpha, quad * 4 + 1);
                const float a2 = __shfl(alpha, quad * 4 + 2);
                const float a3 = __shfl(alpha, quad * 4 + 3);
#pragma unroll
                for (int nt = 0; nt < 4; ++nt) {
                    oaccv[mt][nt][0] *= a0; oaccv[mt][nt][1] *= a1;
                    oaccv[mt][nt][2] *= a2; oaccv[mt][nt][3] *= a3;
                }
            }
        }

        // P = exp2(lg - m), packed bf16 to per-wave LDS; lane-local psum
#pragma unroll
        for (int mt = 0; mt < 2; ++mt) {
            const int prow = mt * 16 + n16;
            const float mn = m_n[mt];
            float psum = 0.f;
#pragma unroll
            for (int nt = 0; nt < 4; ++nt) {
#pragma unroll
                for (int r = 0; r < 4; ++r) lgT[mt][nt][r] = exp2f(lgT[mt][nt][r] - mn);
                u32x2 pk;
                pk[0] = cvt_pk_bf16(lgT[mt][nt][0], lgT[mt][nt][1]);
                pk[1] = cvt_pk_bf16(lgT[mt][nt][2], lgT[mt][nt][3]);
                *(u32x2*)&ps[w][prow][SWZ(prow, nt * 2 + (quad >> 1)) + (quad & 1) * 4] = pk;
                psum += (lgT[mt][nt][0] + lgT[mt][nt][1]) + (lgT[mt][nt][2] + lgT[mt][nt][3]);
            }
            l_n[mt] += psum;
        }

        // PV: V fragments read ONCE, used by both mt.
        short8 pa[2][2];
#pragma unroll
        for (int mt = 0; mt < 2; ++mt) {
            const int prow = mt * 16 + n16;
            pa[mt][0] = *(const short8*)&ps[w][prow][SWZ(prow, quad)];
            pa[mt][1] = *(const short8*)&ps[w][prow][SWZ(prow, quad + 4)];
        }
#pragma unroll
        for (int nt = 0; nt < 4; ++nt) {
            const int row = nt * 16 + n16;
            short8 v0 = *(const short8*)&vTs[cur][row][SWZ(row, quad)];
            short8 v1 = *(const short8*)&vTs[cur][row][SWZ(row, quad + 4)];
#pragma unroll
            for (int mt = 0; mt < 2; ++mt) {
                oaccv[mt][nt] = __builtin_amdgcn_mfma_f32_16x16x32_bf16(pa[mt][0], v0, oaccv[mt][nt], 0, 0, 0);
                oaccv[mt][nt] = __builtin_amdgcn_mfma_f32_16x16x32_bf16(pa[mt][1], v1, oaccv[mt][nt], 0, 0, 0);
            }
        }

        // stage-write next tile into idle buffer (next-iter top barrier syncs)
        if (pf) {
            const int nx = cur ^ 1;
            *(short8*)&khs[nx][srow][scl] = rk0h;  *(short8*)&khs[nx][srow + 32][scl] = rk1h;
            *(short8*)&kls[nx][srow][scl] = rk0l;  *(short8*)&kls[nx][srow + 32][scl] = rk1l;
            *(short8*)&vTs[nx][srow][scl] = rv0;   *(short8*)&vTs[nx][srow + 32][scl] = rv1;
        }
    }

    // epilogue: reduce lane-local l, write o_hi bf16, row-major (b, t, h*64+d)
#pragma unroll
    for (int mt = 0; mt < 2; ++mt) {
        float l = l_n[mt];
        l += __shfl_xor(l, 16);
        l += __shfl_xor(l, 32);
        l_n[mt] = l;
    }
#pragma unroll
    for (int mt = 0; mt < 2; ++mt) {
#pragma unroll
        for (int r = 0; r < 4; ++r) {
            float lr = __shfl(l_n[mt], quad * 4 + r);
            float inv = 1.f / lr;
            int t = t0 + w * 32 + mt * 16 + quad * 4 + r;
#pragma unroll
            for (int nt = 0; nt < 4; ++nt) {
                int d = nt * 16 + n16;
                o[((size_t)(b * SEQ + t)) * D_MODEL + h * HDIM + d] = f2bf(oaccv[mt][nt][r] * inv);
            }
        }
    }
}

// ---------------------------------------------------------------- launcher
extern "C" void kernel_launch(void* const* d_in, const int* in_sizes, int n_in,
                              void* d_out, int out_size, void* d_ws, size_t ws_size,
                              hipStream_t stream) {
    const float* x  = (const float*)d_in[0];
    const float* Wq = (const float*)d_in[1];
    const float* bq = (const float*)d_in[2];
    const float* Wk = (const float*)d_in[3];
    const float* bk = (const float*)d_in[4];
    const float* Wv = (const float*)d_in[5];
    const float* bv = (const float*)d_in[6];
    const float* Wo = (const float*)d_in[7];
    const float* bo = (const float*)d_in[8];
    const float* A  = (const float*)d_in[9];
    const float* ll = (const float*)d_in[10];
    float* out = (float*)d_out;

    const size_t NQKV = (size_t)NROWS * D_MODEL;   // 4,194,304
    const size_t NW = (size_t)D_MODEL * D_MODEL;   // 1,048,576
    char* base = (char*)d_ws;
    float* q_ws = (float*)base;            base += NQKV * 4;
    u16* xh  = (u16*)base;                 base += NQKV * 2;   // reused as o_hi after QKV
    u16* xl  = (u16*)base;                 base += NQKV * 2;   // reused as vT after QKV
    u16* khw = (u16*)base;                 base += NQKV * 2;
    u16* klw = (u16*)base;                 base += NQKV * 2;
    u16* vhw = (u16*)base;                 base += NQKV * 2;
    u16* wqh = (u16*)base;                 base += NW * 2;
    u16* wql = (u16*)base;                 base += NW * 2;
    u16* wkh = (u16*)base;                 base += NW * 2;
    u16* wkl = (u16*)base;                 base += NW * 2;
    u16* wvh = (u16*)base;                 base += NW * 2;
    u16* woh = (u16*)base;                 base += NW * 2;
    float* gd_ws   = (float*)base;         base += NHEAD * HDIM * 4;
    float* ksum_ws = (float*)base;         base += BATCH * NHEAD * HDIM * 4;

    hipMemsetAsync(ksum_ws, 0, BATCH * NHEAD * HDIM * sizeof(float), stream);

    prep_split<<<dim3(4096, 5), 256, 0, stream>>>(x, Wq, Wk, Wv, Wo,
                                                  xh, xl, wqh, wql, wkh, wkl, wvh, woh);
    gdiag_kernel<<<4, 256, 0, stream>>>(A, ll, gd_ws);

    // Q (z=0) + K (z=1): 3-pass split-bf16; K writes k_hi/k_lo + ksum atomics
    gemm_mfma<1><<<dim3(16, 32, 2), 512, 0, stream>>>(
        xh, xl,
        wqh, wql, bq, q_ws, nullptr, nullptr, nullptr,
        wkh, wkl, bk, nullptr, khw, klw, ksum_ws,
        1);
    // V: 1-pass bf16, writes v_hi bf16 only
    gemm_mfma<0><<<dim3(16, 32, 1), 512, 0, stream>>>(
        xh, nullptr,
        wvh, nullptr, bv, nullptr, vhw, nullptr, nullptr,
        wvh, nullptr, bv, nullptr, vhw, nullptr, nullptr,
        1);

    u16* vTw = xl;   // alias: x_lo dead after QKV GEMMs
    u16* ohw = xh;   // alias: x_hi dead after QKV GEMMs
    vtrans_kernel<<<dim3(SEQ / 64, BATCH * NHEAD), 256, 0, stream>>>(vhw, vTw);

    flash_mfma<<<dim3(SEQ / 128, NHEAD, BATCH), 256, 0, stream>>>(
        q_ws, khw, klw, vTw, ksum_ws, gd_ws, ohw);

    // out-proj: 1-pass bf16, row-major fp32 output
    gemm_mfma<0><<<dim3(16, 32, 1), 512, 0, stream>>>(
        ohw, nullptr,
        woh, nullptr, bo, out, nullptr, nullptr, nullptr,
        woh, nullptr, bo, out, nullptr, nullptr, nullptr,
        0);
}

// Round 11
// 297.003 us; speedup vs baseline: 1.1967x; 1.0205x over previous
//
#include <hip/hip_runtime.h>
#include <math.h>

#define D_MODEL 1024
#define NHEAD   16
#define HDIM    64
#define SEQ     2048
#define BATCH   2
#define NROWS   (BATCH*SEQ)   // 4096

typedef unsigned short u16;
typedef __attribute__((ext_vector_type(4))) unsigned short u16x4;
typedef __attribute__((ext_vector_type(8))) short short8;
typedef __attribute__((ext_vector_type(4))) float f32x4;
typedef __attribute__((ext_vector_type(2))) unsigned int u32x2;

// Flash LDS swizzle: 16B chunk c of row r lives at chunk c ^ (r & 7) (8 chunks/row).
#define SWZ(row, c) (((c) ^ ((row) & 7)) * 8)
// GEMM LDS swizzle for [*][32] bf16 tiles (4 chunks/row) — r9-verified.
#define GF(row) ((((row) + ((row) >> 2))) & 3)

// ---- bf16 helpers (RNE) ----
__device__ __forceinline__ u16 f2bf(float x) {
    unsigned int u = __float_as_uint(x);
    u += 0x7fffu + ((u >> 16) & 1u);
    return (u16)(u >> 16);
}
__device__ __forceinline__ float bf2f(u16 h) {
    return __uint_as_float(((unsigned int)h) << 16);
}
// packed f32x2 -> bf16x2 (HW RNE), no builtin on gfx950 -> inline asm
__device__ __forceinline__ unsigned int cvt_pk_bf16(float a, float b) {
    unsigned int r;
    asm("v_cvt_pk_bf16_f32 %0, %1, %2" : "=v"(r) : "v"(a), "v"(b));
    return r;
}
__device__ __forceinline__ void st8(u16* p, short8 v) {
    u16x4 a, b;
    a[0]=(u16)v[0]; a[1]=(u16)v[1]; a[2]=(u16)v[2]; a[3]=(u16)v[3];
    b[0]=(u16)v[4]; b[1]=(u16)v[5]; b[2]=(u16)v[6]; b[3]=(u16)v[7];
    *(u16x4*)p = a; *(u16x4*)(p + 4) = b;
}
// async global->LDS, 16B/lane. LDS dest = wave-uniform base + lane*16 (m104);
// global src is per-lane (pre-swizzled for bank-conflict-free reads, m173).
__device__ __forceinline__ void gld16(const u16* g, u16* l) {
    __builtin_amdgcn_global_load_lds(
        (const __attribute__((address_space(1))) void*)g,
        (__attribute__((address_space(3))) void*)l, 16, 0, 0);
}

// T1 XCD-aware decode (assumes dispatch XCD = linear_bid % 8, 8 XCDs):
// bid = (g&7) + 8*(member + 16*(g>>3))  <=>  all 16 members of group g land on XCD g&7.
// Bijective for gridDim.x in {512, 1024}. Groups share the L2-heavy operand.
__device__ __forceinline__ void xcd_decode(int bid, int& member, int& g) {
    const int xcd = bid & 7;
    const int rest = bid >> 3;
    member = rest & 15;
    g = ((rest >> 4) << 3) | xcd;
}

// ---------------------------------------------------------------- gdiag
__global__ void gdiag_kernel(const float* __restrict__ A,
                             const float* __restrict__ log_lambda,
                             float* __restrict__ gdiag) {
    int id = blockIdx.x * 256 + threadIdx.x;
    if (id >= NHEAD * HDIM) return;
    int h = id >> 6, d = id & 63;
    float s = 0.f;
#pragma unroll
    for (int i = 0; i < 16; ++i) {
        float a = A[(h * 16 + i) * HDIM + d];
        s += a * a;
    }
    gdiag[id] = (s + __expf(log_lambda[h])) * 1.4426950408889634f;
}

// ---------------------------------------------------------------- prep: fp32 -> bf16 hi/lo
__global__ void prep_split(const float* __restrict__ x,
                           const float* __restrict__ Wq, const float* __restrict__ Wk,
                           const float* __restrict__ Wv, const float* __restrict__ Wo,
                           u16* __restrict__ xh, u16* __restrict__ xl,
                           u16* __restrict__ wqh, u16* __restrict__ wql,
                           u16* __restrict__ wkh, u16* __restrict__ wkl,
                           u16* __restrict__ wvh, u16* __restrict__ woh) {
    int seg = blockIdx.y;
    int i = blockIdx.x * 256 + threadIdx.x;   // float4 index
    const float* src; u16* dh; u16* dl; int n4;
    if      (seg == 0) { src = x;  dh = xh;  dl = xl;      n4 = NROWS * D_MODEL / 4; }
    else if (seg == 1) { src = Wq; dh = wqh; dl = wql;     n4 = D_MODEL * D_MODEL / 4; }
    else if (seg == 2) { src = Wk; dh = wkh; dl = wkl;     n4 = D_MODEL * D_MODEL / 4; }
    else if (seg == 3) { src = Wv; dh = wvh; dl = nullptr; n4 = D_MODEL * D_MODEL / 4; }
    else               { src = Wo; dh = woh; dl = nullptr; n4 = D_MODEL * D_MODEL / 4; }
    if (i >= n4) return;
    float4 v = *(const float4*)&src[(size_t)i * 4];
    float vv[4] = {v.x, v.y, v.z, v.w};
    u16x4 hv, lv;
#pragma unroll
    for (int j = 0; j < 4; ++j) {
        u16 hb = f2bf(vv[j]);
        hv[j] = hb;
        lv[j] = f2bf(vv[j] - bf2f(hb));
    }
    *(u16x4*)&dh[(size_t)i * 4] = hv;
    if (dl) *(u16x4*)&dl[(size_t)i * 4] = lv;
}

// ---------------------------------------------------------------- MFMA NT GEMM (r10 geometry + T1 swizzle)
// out[r][c] = sum_k A[r][k]*W[c][k] + bias[c]; A,W in bf16 hi(/lo), fp32 acc.
// Tile 128x64, BK=32, 512 threads (8 waves), wave = 16 rows x 64 cols -> acc 16 AGPR.
// 1-D grid; xcd_decode: member = col-tile x (16 per group), g = y + 32*z -> the 16
// col-tiles sharing one 128-row A panel co-locate on one XCD's L2.
template<int NP3>
__global__ __launch_bounds__(512, 4)
void gemm_mfma(const u16* __restrict__ Ah, const u16* __restrict__ Al,
               const u16* __restrict__ BhA, const u16* __restrict__ BlA, const float* __restrict__ biasA,
               float* outfA, u16* auxhA, u16* auxlA, float* ksumA,
               const u16* __restrict__ BhB, const u16* __restrict__ BlB, const float* __restrict__ biasB,
               float* outfB, u16* auxhB, u16* auxlB, float* ksumB,
               int out_layout) {
    int xtile, g;
    xcd_decode(blockIdx.x, xtile, g);
    const int ytile = g & 31;
    const int z = g >> 5;

    const u16* Bh = (z == 0) ? BhA : BhB;
    const u16* Bl = (z == 0) ? BlA : BlB;
    const float* bias = (z == 0) ? biasA : biasB;
    float* outf = (z == 0) ? outfA : outfB;
    u16* auxh   = (z == 0) ? auxhA : auxhB;
    u16* auxl   = (z == 0) ? auxlA : auxlB;
    float* ksump= (z == 0) ? ksumA : ksumB;

    __shared__ __align__(16) u16 As_h[128][32], Bs_h[64][32];
    __shared__ __align__(16) u16 As_l[NP3 ? 128 : 1][32], Bs_l[NP3 ? 64 : 1][32];

    const int tid = threadIdx.x;
    const int w = tid >> 6, lane = tid & 63, quad = lane >> 4, n16 = lane & 15;
    const int rBase = ytile * 128;
    const int cBase = xtile * 64;

    const int lrow = lane >> 2;          // 0..15
    const int lch  = lane & 3;
    const int arow = w * 16 + lrow;      // A rows for this wave
    const int asc  = ((lch ^ GF(arow)) * 8);
    const int brow = (w & 3) * 16 + lrow;  // B rows (waves 0-3: B_h; waves 4-7: B_l)
    const int bsc  = ((lch ^ GF(brow)) * 8);

    f32x4 acc[4] = {};

    for (int kt = 0; kt < D_MODEL; kt += 32) {
        gld16(&Ah[(size_t)(rBase + arow) * D_MODEL + kt + asc], &As_h[w * 16][0]);
        if (NP3) gld16(&Al[(size_t)(rBase + arow) * D_MODEL + kt + asc], &As_l[w * 16][0]);
        if (w < 4) {
            gld16(&Bh[(size_t)(cBase + brow) * D_MODEL + kt + bsc], &Bs_h[(w & 3) * 16][0]);
        } else if (NP3) {
            gld16(&Bl[(size_t)(cBase + brow) * D_MODEL + kt + bsc], &Bs_l[NP3 ? (w & 3) * 16 : 0][0]);
        }
        __syncthreads();   // compiler drains vmcnt before barrier -> LDS ready

        short8 a_h, a_l;
        {
            const int row = w * 16 + n16;
            const int cc = (quad ^ GF(row)) * 8;
            a_h = *(const short8*)&As_h[row][cc];
            if (NP3) a_l = *(const short8*)&As_l[NP3 ? row : 0][cc];
        }
#pragma unroll
        for (int nt = 0; nt < 4; ++nt) {
            const int row = nt * 16 + n16;
            const int cc = (quad ^ GF(row)) * 8;
            short8 b_h = *(const short8*)&Bs_h[row][cc];
            short8 b_l;
            if (NP3) b_l = *(const short8*)&Bs_l[NP3 ? row : 0][cc];
            acc[nt] = __builtin_amdgcn_mfma_f32_16x16x32_bf16(a_h, b_h, acc[nt], 0, 0, 0);
            if (NP3) {
                acc[nt] = __builtin_amdgcn_mfma_f32_16x16x32_bf16(a_h, b_l, acc[nt], 0, 0, 0);
                acc[nt] = __builtin_amdgcn_mfma_f32_16x16x32_bf16(a_l, b_h, acc[nt], 0, 0, 0);
            }
        }
        __syncthreads();
    }

    // epilogue: C row = quad*4+reg (within 16x16 tile), col = n16
    float csum[4];
#pragma unroll
    for (int nt = 0; nt < 4; ++nt) csum[nt] = 0.f;
#pragma unroll
    for (int nt = 0; nt < 4; ++nt) {
        int c = cBase + nt * 16 + n16;
        float bc = bias[c];
        int rb = rBase + w * 16 + quad * 4;
#pragma unroll
        for (int reg = 0; reg < 4; ++reg) {
            float val = acc[nt][reg] + bc;
            int rr = rb + reg;
            size_t idx = out_layout
                ? ((size_t)(((rr >> 11) * NHEAD + (c >> 6)) * SEQ + (rr & (SEQ - 1)))) * HDIM + (c & 63)
                : (size_t)rr * D_MODEL + c;
            if (outf) outf[idx] = val;
            if (auxh) {
                u16 hb = f2bf(val);
                auxh[idx] = hb;
                if (auxl) auxl[idx] = f2bf(val - bf2f(hb));
            }
            csum[nt] += val;
        }
    }
    if (ksump) {
#pragma unroll
        for (int nt = 0; nt < 4; ++nt) {
            float cs = csum[nt];
            cs += __shfl_xor(cs, 16);
            cs += __shfl_xor(cs, 32);
            if (quad == 0) {
                int c = cBase + nt * 16 + n16;
                int bb = rBase >> 11;
                atomicAdd(&ksump[(bb * NHEAD + (c >> 6)) * HDIM + (c & 63)], cs);
            }
        }
    }
}

// ---------------------------------------------------------------- v transpose: (b,h,t,hd) bf16 -> (b,h,hd,t) bf16
__global__ __launch_bounds__(256)
void vtrans_kernel(const u16* __restrict__ vh, u16* __restrict__ vT) {
    __shared__ u16 tile[64][72];
    const int tid = threadIdx.x;
    const int t0 = blockIdx.x * 64;
    const int bh = blockIdx.y;
    const u16* vp = vh + (size_t)bh * SEQ * HDIM;
#pragma unroll
    for (int s = 0; s < 2; ++s) {
        int id = s * 256 + tid;
        int row = id >> 3, c8 = (id & 7) * 8;
        st8(&tile[row][c8], *(const short8*)&vp[(size_t)(t0 + row) * HDIM + c8]);
    }
    __syncthreads();
#pragma unroll
    for (int s = 0; s < 2; ++s) {
        int id = s * 256 + tid;
        int d = id >> 3, t8 = (id & 7) * 8;
        short8 r;
#pragma unroll
        for (int i = 0; i < 8; ++i) r[i] = (short)tile[t8 + i][d];
        *(short8*)&vT[((size_t)bh * HDIM + d) * SEQ + t0 + t8] = r;
    }
}

// ---------------------------------------------------------------- flash attention (round-3 structure + T1 swizzle)
// QBLK=128: 4 waves x 32 queries (2 fragments mt). K/V LDS double-buffered (one barrier
// per tile); XOR chunk swizzle. Swapped-operand QK^T; T13 defer-max; lane-local l.
// 1-D grid (512); xcd_decode: member = q-block (16 per group), g = h + 16*b -> the 16
// q-blocks sharing one (b,h)'s K/V co-locate on one XCD's L2 (K/V = 768 KB << 4 MB L2).
__global__ __launch_bounds__(256, 2)
void flash_mfma(const float* __restrict__ q, const u16* __restrict__ kh,
                const u16* __restrict__ kl, const u16* __restrict__ vT,
                const float* __restrict__ ksum, const float* __restrict__ gdiag,
                u16* __restrict__ o) {
    __shared__ __align__(16) u16 khs[2][64][64], kls[2][64][64], vTs[2][64][64];
    __shared__ __align__(16) u16 ps[4][32][64];

    const int tid = threadIdx.x;
    const int w = tid >> 6, lane = tid & 63, quad = lane >> 4, n16 = lane & 15;
    int qblk, g;
    xcd_decode(blockIdx.x, qblk, g);
    const int t0 = qblk * 128;
    const int h = g & 15, b = g >> 4;
    const size_t bh = (size_t)b * NHEAD + h;
    const float* qp = q + bh * SEQ * HDIM;
    const u16* khp = kh + bh * SEQ * HDIM;
    const u16* klp = kl + bh * SEQ * HDIM;
    const u16* vtp = vT + bh * HDIM * SEQ;

    // Sg fragments: sg*[mt][kc][j], d = kc*32 + quad*8 + j, query = t0+w*32+mt*16+n16
    short8 sgh[2][2], sgl[2][2];
#pragma unroll
    for (int mt = 0; mt < 2; ++mt) {
        int qrow = t0 + w * 32 + mt * 16 + n16;
#pragma unroll
        for (int kc = 0; kc < 2; ++kc) {
            int d0 = kc * 32 + quad * 8;
            float4 q0 = *(const float4*)&qp[(size_t)qrow * HDIM + d0];
            float4 q1 = *(const float4*)&qp[(size_t)qrow * HDIM + d0 + 4];
            float4 k0 = *(const float4*)&ksum[bh * HDIM + d0];
            float4 k1 = *(const float4*)&ksum[bh * HDIM + d0 + 4];
            float4 g0 = *(const float4*)&gdiag[(size_t)h * HDIM + d0];
            float4 g1 = *(const float4*)&gdiag[(size_t)h * HDIM + d0 + 4];
            float sg[8];
            sg[0] = (2048.f * q0.x - k0.x) * g0.x; sg[1] = (2048.f * q0.y - k0.y) * g0.y;
            sg[2] = (2048.f * q0.z - k0.z) * g0.z; sg[3] = (2048.f * q0.w - k0.w) * g0.w;
            sg[4] = (2048.f * q1.x - k1.x) * g1.x; sg[5] = (2048.f * q1.y - k1.y) * g1.y;
            sg[6] = (2048.f * q1.z - k1.z) * g1.z; sg[7] = (2048.f * q1.w - k1.w) * g1.w;
#pragma unroll
            for (int j = 0; j < 8; ++j) {
                u16 hb = f2bf(sg[j]);
                sgh[mt][kc][j] = (short)hb;
                sgl[mt][kc][j] = (short)f2bf(sg[j] - bf2f(hb));
            }
        }
    }

    f32x4 oaccv[2][4] = {};
    float m_n[2] = {-INFINITY, -INFINITY};
    float l_n[2] = {0.f, 0.f};     // lane-local partial sums; reduced in epilogue

    const int srow = tid >> 3;            // 0..31
    const int sc   = tid & 7;             // chunk
    const int scg  = sc * 8;              // global u16 col
    const int scl  = SWZ(srow, sc);       // LDS u16 col

    // prologue: load+store tile j0=0 into buffer 0
    short8 rk0h = *(const short8*)&khp[(size_t)srow * HDIM + scg];
    short8 rk1h = *(const short8*)&khp[(size_t)(srow + 32) * HDIM + scg];
    short8 rk0l = *(const short8*)&klp[(size_t)srow * HDIM + scg];
    short8 rk1l = *(const short8*)&klp[(size_t)(srow + 32) * HDIM + scg];
    short8 rv0  = *(const short8*)&vtp[(size_t)srow * SEQ + scg];
    short8 rv1  = *(const short8*)&vtp[(size_t)(srow + 32) * SEQ + scg];
    *(short8*)&khs[0][srow][scl] = rk0h;  *(short8*)&khs[0][srow + 32][scl] = rk1h;
    *(short8*)&kls[0][srow][scl] = rk0l;  *(short8*)&kls[0][srow + 32][scl] = rk1l;
    *(short8*)&vTs[0][srow][scl] = rv0;   *(short8*)&vTs[0][srow + 32][scl] = rv1;

    int cur = 0;
    for (int j0 = 0; j0 < SEQ; j0 += 64, cur ^= 1) {
        __syncthreads();   // buf[cur] staged; buf[cur^1] free to overwrite
        const int jn = j0 + 64;
        const bool pf = (jn < SEQ);
        if (pf) {
            rk0h = *(const short8*)&khp[(size_t)(jn + srow) * HDIM + scg];
            rk1h = *(const short8*)&khp[(size_t)(jn + srow + 32) * HDIM + scg];
            rk0l = *(const short8*)&klp[(size_t)(jn + srow) * HDIM + scg];
            rk1l = *(const short8*)&klp[(size_t)(jn + srow + 32) * HDIM + scg];
            rv0  = *(const short8*)&vtp[(size_t)srow * SEQ + jn + scg];
            rv1  = *(const short8*)&vtp[(size_t)(srow + 32) * SEQ + jn + scg];
        }

        // QK^T: K fragments read ONCE, used by both mt. 3-pass split bf16.
        f32x4 lgT[2][4] = {};
#pragma unroll
        for (int kc = 0; kc < 2; ++kc) {
#pragma unroll
            for (int nt = 0; nt < 4; ++nt) {
                const int row = nt * 16 + n16;
                const int cc = SWZ(row, kc * 4 + quad);
                short8 b_h = *(const short8*)&khs[cur][row][cc];
                short8 b_l = *(const short8*)&kls[cur][row][cc];
#pragma unroll
                for (int mt = 0; mt < 2; ++mt) {
                    lgT[mt][nt] = __builtin_amdgcn_mfma_f32_16x16x32_bf16(b_h, sgh[mt][kc], lgT[mt][nt], 0, 0, 0);
                    lgT[mt][nt] = __builtin_amdgcn_mfma_f32_16x16x32_bf16(b_l, sgh[mt][kc], lgT[mt][nt], 0, 0, 0);
                    lgT[mt][nt] = __builtin_amdgcn_mfma_f32_16x16x32_bf16(b_h, sgl[mt][kc], lgT[mt][nt], 0, 0, 0);
                }
            }
        }

        // tile max per query fragment
        float mx[2];
#pragma unroll
        for (int mt = 0; mt < 2; ++mt) {
            float m0 = fmaxf(fmaxf(lgT[mt][0][0], lgT[mt][0][1]), lgT[mt][0][2]);
            m0 = fmaxf(fmaxf(m0, lgT[mt][0][3]), lgT[mt][1][0]);
            m0 = fmaxf(fmaxf(m0, lgT[mt][1][1]), lgT[mt][1][2]);
            m0 = fmaxf(fmaxf(m0, lgT[mt][1][3]), lgT[mt][2][0]);
            m0 = fmaxf(fmaxf(m0, lgT[mt][2][1]), lgT[mt][2][2]);
            m0 = fmaxf(fmaxf(m0, lgT[mt][2][3]), lgT[mt][3][0]);
            m0 = fmaxf(fmaxf(m0, lgT[mt][3][1]), lgT[mt][3][2]);
            m0 = fmaxf(m0, lgT[mt][3][3]);
            m0 = fmaxf(m0, __shfl_xor(m0, 16));
            mx[mt] = fmaxf(m0, __shfl_xor(m0, 32));
        }

        // T13 defer-max
        const float need = fmaxf(mx[0] - m_n[0], mx[1] - m_n[1]);
        if (!__all(need <= 8.f)) {
#pragma unroll
            for (int mt = 0; mt < 2; ++mt) {
                const float mn = fmaxf(m_n[mt], mx[mt]);
                const float alpha = exp2f(m_n[mt] - mn);
                m_n[mt] = mn;
                l_n[mt] *= alpha;
                const float a0 = __shfl(alpha, quad * 4 + 0);
                const float a1 = __shfl(alpha, quad * 4 + 1);
                const float a2 = __shfl(alpha, quad * 4 + 2);
                const float a3 = __shfl(alpha, quad * 4 + 3);
#pragma unroll
                for (int nt = 0; nt < 4; ++nt) {
                    oaccv[mt][nt][0] *= a0; oaccv[mt][nt][1] *= a1;
                    oaccv[mt][nt][2] *= a2; oaccv[mt][nt][3] *= a3;
                }
            }
        }

        // P = exp2(lg - m), packed bf16 to per-wave LDS; lane-local psum
#pragma unroll
        for (int mt = 0; mt < 2; ++mt) {
            const int prow = mt * 16 + n16;
            const float mn = m_n[mt];
            float psum = 0.f;
#pragma unroll
            for (int nt = 0; nt < 4; ++nt) {
#pragma unroll
                for (int r = 0; r < 4; ++r) lgT[mt][nt][r] = exp2f(lgT[mt][nt][r] - mn);
                u32x2 pk;
                pk[0] = cvt_pk_bf16(lgT[mt][nt][0], lgT[mt][nt][1]);
                pk[1] = cvt_pk_bf16(lgT[mt][nt][2], lgT[mt][nt][3]);
                *(u32x2*)&ps[w][prow][SWZ(prow, nt * 2 + (quad >> 1)) + (quad & 1) * 4] = pk;
                psum += (lgT[mt][nt][0] + lgT[mt][nt][1]) + (lgT[mt][nt][2] + lgT[mt][nt][3]);
            }
            l_n[mt] += psum;
        }

        // PV: V fragments read ONCE, used by both mt.
        short8 pa[2][2];
#pragma unroll
        for (int mt = 0; mt < 2; ++mt) {
            const int prow = mt * 16 + n16;
            pa[mt][0] = *(const short8*)&ps[w][prow][SWZ(prow, quad)];
            pa[mt][1] = *(const short8*)&ps[w][prow][SWZ(prow, quad + 4)];
        }
#pragma unroll
        for (int nt = 0; nt < 4; ++nt) {
            const int row = nt * 16 + n16;
            short8 v0 = *(const short8*)&vTs[cur][row][SWZ(row, quad)];
            short8 v1 = *(const short8*)&vTs[cur][row][SWZ(row, quad + 4)];
#pragma unroll
            for (int mt = 0; mt < 2; ++mt) {
                oaccv[mt][nt] = __builtin_amdgcn_mfma_f32_16x16x32_bf16(pa[mt][0], v0, oaccv[mt][nt], 0, 0, 0);
                oaccv[mt][nt] = __builtin_amdgcn_mfma_f32_16x16x32_bf16(pa[mt][1], v1, oaccv[mt][nt], 0, 0, 0);
            }
        }

        // stage-write next tile into idle buffer (next-iter top barrier syncs)
        if (pf) {
            const int nx = cur ^ 1;
            *(short8*)&khs[nx][srow][scl] = rk0h;  *(short8*)&khs[nx][srow + 32][scl] = rk1h;
            *(short8*)&kls[nx][srow][scl] = rk0l;  *(short8*)&kls[nx][srow + 32][scl] = rk1l;
            *(short8*)&vTs[nx][srow][scl] = rv0;   *(short8*)&vTs[nx][srow + 32][scl] = rv1;
        }
    }

    // epilogue: reduce lane-local l, write o_hi bf16, row-major (b, t, h*64+d)
#pragma unroll
    for (int mt = 0; mt < 2; ++mt) {
        float l = l_n[mt];
        l += __shfl_xor(l, 16);
        l += __shfl_xor(l, 32);
        l_n[mt] = l;
    }
#pragma unroll
    for (int mt = 0; mt < 2; ++mt) {
#pragma unroll
        for (int r = 0; r < 4; ++r) {
            float lr = __shfl(l_n[mt], quad * 4 + r);
            float inv = 1.f / lr;
            int t = t0 + w * 32 + mt * 16 + quad * 4 + r;
#pragma unroll
            for (int nt = 0; nt < 4; ++nt) {
                int d = nt * 16 + n16;
                o[((size_t)(b * SEQ + t)) * D_MODEL + h * HDIM + d] = f2bf(oaccv[mt][nt][r] * inv);
            }
        }
    }
}

// ---------------------------------------------------------------- launcher
extern "C" void kernel_launch(void* const* d_in, const int* in_sizes, int n_in,
                              void* d_out, int out_size, void* d_ws, size_t ws_size,
                              hipStream_t stream) {
    const float* x  = (const float*)d_in[0];
    const float* Wq = (const float*)d_in[1];
    const float* bq = (const float*)d_in[2];
    const float* Wk = (const float*)d_in[3];
    const float* bk = (const float*)d_in[4];
    const float* Wv = (const float*)d_in[5];
    const float* bv = (const float*)d_in[6];
    const float* Wo = (const float*)d_in[7];
    const float* bo = (const float*)d_in[8];
    const float* A  = (const float*)d_in[9];
    const float* ll = (const float*)d_in[10];
    float* out = (float*)d_out;

    const size_t NQKV = (size_t)NROWS * D_MODEL;   // 4,194,304
    const size_t NW = (size_t)D_MODEL * D_MODEL;   // 1,048,576
    char* base = (char*)d_ws;
    float* q_ws = (float*)base;            base += NQKV * 4;
    u16* xh  = (u16*)base;                 base += NQKV * 2;   // reused as o_hi after QKV
    u16* xl  = (u16*)base;                 base += NQKV * 2;   // reused as vT after QKV
    u16* khw = (u16*)base;                 base += NQKV * 2;
    u16* klw = (u16*)base;                 base += NQKV * 2;
    u16* vhw = (u16*)base;                 base += NQKV * 2;
    u16* wqh = (u16*)base;                 base += NW * 2;
    u16* wql = (u16*)base;                 base += NW * 2;
    u16* wkh = (u16*)base;                 base += NW * 2;
    u16* wkl = (u16*)base;                 base += NW * 2;
    u16* wvh = (u16*)base;                 base += NW * 2;
    u16* woh = (u16*)base;                 base += NW * 2;
    float* gd_ws   = (float*)base;         base += NHEAD * HDIM * 4;
    float* ksum_ws = (float*)base;         base += BATCH * NHEAD * HDIM * 4;

    hipMemsetAsync(ksum_ws, 0, BATCH * NHEAD * HDIM * sizeof(float), stream);

    prep_split<<<dim3(4096, 5), 256, 0, stream>>>(x, Wq, Wk, Wv, Wo,
                                                  xh, xl, wqh, wql, wkh, wkl, wvh, woh);
    gdiag_kernel<<<4, 256, 0, stream>>>(A, ll, gd_ws);

    // Q (g<32) + K (g>=32): 3-pass split-bf16; K writes k_hi/k_lo + ksum atomics
    gemm_mfma<1><<<1024, 512, 0, stream>>>(
        xh, xl,
        wqh, wql, bq, q_ws, nullptr, nullptr, nullptr,
        wkh, wkl, bk, nullptr, khw, klw, ksum_ws,
        1);
    // V: 1-pass bf16, writes v_hi bf16 only
    gemm_mfma<0><<<512, 512, 0, stream>>>(
        xh, nullptr,
        wvh, nullptr, bv, nullptr, vhw, nullptr, nullptr,
        wvh, nullptr, bv, nullptr, vhw, nullptr, nullptr,
        1);

    u16* vTw = xl;   // alias: x_lo dead after QKV GEMMs
    u16* ohw = xh;   // alias: x_hi dead after QKV GEMMs
    vtrans_kernel<<<dim3(SEQ / 64, BATCH * NHEAD), 256, 0, stream>>>(vhw, vTw);

    flash_mfma<<<512, 256, 0, stream>>>(
        q_ws, khw, klw, vTw, ksum_ws, gd_ws, ohw);

    // out-proj: 1-pass bf16, row-major fp32 output
    gemm_mfma<0><<<512, 512, 0, stream>>>(
        ohw, nullptr,
        woh, nullptr, bo, out, nullptr, nullptr, nullptr,
        woh, nullptr, bo, out, nullptr, nullptr, nullptr,
        0);
}